// Round 3
// baseline (161.078 us; speedup 1.0000x reference)
//
#include <hip/hip_runtime.h>
#include <hip/hip_bf16.h>

// Problem constants
#define BATCH 2
#define GRP   2
#define NBG   4            // BATCH*GRP
#define CINCH 192          // input channels
#define OG    192          // output channels per group
#define HWDIM 48
#define LPIX  2304         // 48*48
#define KTAP  25           // 5x5
#define IDIM  4800         // CINCH*KTAP
#define NCHUNK 150         // IDIM/32
#define KSPLIT 5           // 5 taps (one kernel row) per split
#define XPAD  24576        // 128 l-rows * 192 c of zeroed padding each side

typedef __attribute__((ext_vector_type(4))) float  float4v;
typedef __attribute__((ext_vector_type(8))) short  short8;

// Static device scratch
__device__ unsigned short g_wr[NBG * NCHUNK * OG * 32];            // [bg][t][o][k32] bf16
__device__ __align__(16) unsigned short g_xt[XPAD + BATCH * LPIX * CINCH + XPAD]; // padded [b][l][c]
__device__ unsigned long long g_m64[NBG * LPIX];                   // 50 mask bits per (bg,l)

__device__ __forceinline__ unsigned short f2bf(float f) {
  union { float f; unsigned int u; } un; un.f = f;
  unsigned int u = un.u;
  return (unsigned short)((u + 0x7fffu + ((u >> 16) & 1u)) >> 16);  // RNE
}

// ---------------------------------------------------------------------------
// K0: transpose+convert x fp32 [b][c][l] -> bf16 g_xt [b][l][c] (past front pad).
// 64c x 64l tiles via LDS (row stride 68 shorts: 8B-aligned rows, conflict-lite).
__global__ void transpose_x(const float* __restrict__ x) {
  __shared__ unsigned short tile[64 * 68];
  const int c0 = blockIdx.x * 64, l0 = blockIdx.y * 64, b = blockIdx.z;
  const int tid = threadIdx.x;
  // Phase 1: coalesced float4 reads, cvt, 8B LDS writes
  #pragma unroll
  for (int it = 0; it < 4; ++it) {
    const int idx = it * 256 + tid;          // 0..1023
    const int cl = idx >> 4, lq = idx & 15;  // c row, float4 slot
    const float4 v = reinterpret_cast<const float4*>(
        x + ((size_t)b * CINCH + c0 + cl) * LPIX + l0)[lq];
    unsigned short* tp = &tile[cl * 68 + lq * 4];
    tp[0] = f2bf(v.x); tp[1] = f2bf(v.y); tp[2] = f2bf(v.z); tp[3] = f2bf(v.w);
  }
  __syncthreads();
  // Phase 2: gather 8 c's per l, 16B coalesced global store
  unsigned short* dst = g_xt + XPAD + ((size_t)b * LPIX) * CINCH;
  #pragma unroll
  for (int it = 0; it < 2; ++it) {
    const int idx = it * 256 + tid;          // 0..511
    const int c8 = idx & 7, ll = idx >> 3;   // 8-c group, l row
    unsigned short pk[8];
    #pragma unroll
    for (int e = 0; e < 8; ++e) pk[e] = tile[(c8 * 8 + e) * 68 + ll];
    *reinterpret_cast<uint4*>(dst + (size_t)(l0 + ll) * CINCH + c0 + c8 * 8) =
        *reinterpret_cast<const uint4*>(pk);
  }
}

// ---------------------------------------------------------------------------
// K1: reorder dkw (fp32, [bg][o][i=c*25+kk]) -> g_wr (bf16, chunk-major
// [bg][t][o][k]), i' = kk*192 + c, t = i'/32, k = i'%32. Vector 16B stores.
__global__ void reorder_w(const float* __restrict__ dkw) {
  __shared__ float row[IDIM];
  const int blk = blockIdx.x;                 // bg*192 + o
  const int bg = blk / OG, o = blk % OG;
  const float* src = dkw + (size_t)blk * IDIM;
  for (int i = threadIdx.x; i < IDIM / 4; i += 256)
    reinterpret_cast<float4*>(row)[i] = reinterpret_cast<const float4*>(src)[i];
  __syncthreads();
  for (int idx = threadIdx.x; idx < IDIM / 8; idx += 256) {  // 600 x 16B outputs
    const int i0 = idx * 8;
    const int kk = i0 / CINCH, c0 = i0 % CINCH;
    const int t = i0 >> 5, k0 = i0 & 31;
    unsigned int pk[4];
    #pragma unroll
    for (int e = 0; e < 4; ++e) {
      const unsigned lo = f2bf(row[(c0 + 2 * e) * KTAP + kk]);
      const unsigned hi = f2bf(row[(c0 + 2 * e + 1) * KTAP + kk]);
      pk[e] = lo | (hi << 16);
    }
    *reinterpret_cast<uint4*>(
        &g_wr[(((size_t)bg * NCHUNK + t) * OG + o) * 32 + k0]) =
        *reinterpret_cast<const uint4*>(pk);
  }
}

// ---------------------------------------------------------------------------
// K2: mask bits, one block per (bg, h-row); blocks >= 192 zero the g_xt pads.
// mask(b,g,g2,kk,l) = inbounds && tg[b,g2,hh,ww] < tg[b,g,h,w]
__global__ void build_mask(const int* __restrict__ tg) {
  const int blk = blockIdx.x, t = threadIdx.x;
  if (blk >= NBG * HWDIM) {                  // pad zeroing: 96 blocks x 64 thr x 16B
    const int idx = (blk - NBG * HWDIM) * 64 + t;   // 0..6143
    ulonglong2 z; z.x = 0ull; z.y = 0ull;
    if (idx < 3072)
      reinterpret_cast<ulonglong2*>(g_xt)[idx] = z;
    else
      reinterpret_cast<ulonglong2*>(g_xt + XPAD + (size_t)BATCH * LPIX * CINCH)[idx - 3072] = z;
    return;
  }
  const int bg = blk / HWDIM, h = blk % HWDIM;
  const int b = bg >> 1, g = bg & 1;
  __shared__ int tgs[2][5][HWDIM];
  for (int i = t; i < 2 * 5 * HWDIM; i += 64) {
    const int g2 = i / (5 * HWDIM), r = (i / HWDIM) % 5, w = i % HWDIM;
    const int hh = h + r - 2;
    tgs[g2][r][w] = (hh >= 0 && hh < HWDIM)
                        ? tg[((b * GRP + g2) * HWDIM + hh) * HWDIM + w]
                        : 0x7fffffff;
  }
  __syncthreads();
  if (t >= HWDIM) return;
  const int w = t;
  const int center = tgs[g][2][w];
  unsigned long long bits = 0ull;
  #pragma unroll
  for (int g2 = 0; g2 < GRP; ++g2)
    #pragma unroll
    for (int kk = 0; kk < KTAP; ++kk) {
      const int ww = w + kk % 5 - 2;
      if (ww >= 0 && ww < HWDIM && tgs[g2][kk / 5][ww] < center)
        bits |= 1ull << (g2 * KTAP + kk);
    }
  g_m64[bg * LPIX + h * HWDIM + w] = bits;
}

// ---------------------------------------------------------------------------
// K3: fused masked GEMM, no LDS/barriers, branchless, 2-deep pipelined.
// Block: o64 x l256, 4 waves; wave tile o64 x l64 = 4x4 mfma_f32_16x16x32_bf16.
// K-split over kernel rows (ks = kh): 5 taps x 6 chunks, fully unrolled.
// Masked B loads redirect to the zeroed pad (address cndmask, no branches).
__global__ __launch_bounds__(256, 2) void gemm_masked(
    const float* __restrict__ dkb, float* __restrict__ out) {
  const int ltile = blockIdx.x;              // 0..8   (l-tile of 256)
  const int otile = blockIdx.y;              // 0..2   (o-tile of 64)
  const int bg    = blockIdx.z & 3;
  const int ks    = blockIdx.z >> 2;         // 0..4 = kernel row kh
  const int b     = bg >> 1;
  const int lbase = ltile * 256, obase = otile * 64;
  const int tid = threadIdx.x, lane = tid & 63, wv = tid >> 6;
  const int q = lane >> 4, m16 = lane & 15;

  const unsigned short* zp = g_xt + q * 8;   // zeroed front pad
  const unsigned short* xim = g_xt + XPAD + (size_t)b * LPIX * CINCH + q * 8;
  const int sdh = (ks - 2) * HWDIM * CINCH;  // h-offset of this kernel row

  unsigned bl[4], bh[4];
  const unsigned short* xbase[4];
  #pragma unroll
  for (int j = 0; j < 4; ++j) {
    const int lj = lbase + wv * 64 + j * 16 + m16;
    const unsigned long long bits = g_m64[bg * LPIX + lj];
    bl[j] = (unsigned)(bits & 0x1ffffffull);          // g2=0 bits
    bh[j] = (unsigned)(bits >> KTAP) & 0x1ffffffu;    // g2=1 bits
    xbase[j] = xim + (size_t)lj * CINCH + sdh;
  }

  // A lane base: chunks for this block start at t0 = ks*30
  const unsigned short* alane =
      g_wr + (((size_t)bg * NCHUNK + ks * 30) * OG + obase) * 32 + m16 * 32 + q * 8;
  const int ks5 = ks * 5;

  float4v acc[4][4];
  #pragma unroll
  for (int i = 0; i < 4; ++i)
    #pragma unroll
    for (int j = 0; j < 4; ++j) acc[i][j] = (float4v)(0.0f);

  short8 Af[3][4], Bf[3][4];

  auto loadst = [&](int tt) {
    const int s = tt % 3;
    const int kt = tt / 6, ci = tt % 6;      // compile-time under full unroll
    const int imm = (kt - 2) * CINCH + ci * 32;
    const int kk = ks5 + kt;
    #pragma unroll
    for (int i = 0; i < 4; ++i)
      Af[s][i] = *reinterpret_cast<const short8*>(
          alane + (size_t)tt * (OG * 32) + i * (16 * 32));
    #pragma unroll
    for (int j = 0; j < 4; ++j) {
      const unsigned bsel = (ci >= 3) ? bh[j] : bl[j];
      const unsigned short* p = ((bsel >> kk) & 1u) ? (xbase[j] + imm) : zp;
      Bf[s][j] = *reinterpret_cast<const short8*>(p);
    }
  };

  loadst(0);
  loadst(1);
  #pragma unroll
  for (int tt = 0; tt < 30; ++tt) {
    if (tt + 2 < 30) loadst(tt + 2);
    const int s = tt % 3;
    #pragma unroll
    for (int i = 0; i < 4; ++i)
      #pragma unroll
      for (int j = 0; j < 4; ++j)
        acc[i][j] = __builtin_amdgcn_mfma_f32_16x16x32_bf16(Af[s][i], Bf[s][j],
                                                            acc[i][j], 0, 0, 0);
  }

  // Epilogue: C/D layout col = lane&15, row = q*4 + reg. Bias added by ks==0.
  #pragma unroll
  for (int i = 0; i < 4; ++i) {
    const int og = obase + i * 16 + q * 4;
    #pragma unroll
    for (int j = 0; j < 4; ++j) {
      const int cl = lbase + wv * 64 + j * 16 + m16;
      #pragma unroll
      for (int r = 0; r < 4; ++r) {
        float v = acc[i][j][r];
        if (ks == 0) v += dkb[bg * OG + og + r];
        atomicAdd(&out[(size_t)(bg * OG + og + r) * LPIX + cl], v);
      }
    }
  }
}

// ---------------------------------------------------------------------------
extern "C" void kernel_launch(void* const* d_in, const int* in_sizes, int n_in,
                              void* d_out, int out_size, void* d_ws, size_t ws_size,
                              hipStream_t stream) {
  const float* x   = (const float*)d_in[0];
  const int*   tg  = (const int*)d_in[1];
  const float* dkw = (const float*)d_in[2];
  const float* dkb = (const float*)d_in[3];
  float* out = (float*)d_out;

  transpose_x<<<dim3(CINCH / 64, LPIX / 64, BATCH), 256, 0, stream>>>(x);
  reorder_w<<<dim3(NBG * OG), 256, 0, stream>>>(dkw);
  build_mask<<<dim3(NBG * HWDIM + 96), 64, 0, stream>>>(tg);
  hipMemsetAsync(d_out, 0, (size_t)out_size * sizeof(float), stream);
  gemm_masked<<<dim3(9, 3, NBG * KSPLIT), 256, 0, stream>>>(dkb, out);
}

// Round 4
// 152.537 us; speedup vs baseline: 1.0560x; 1.0560x over previous
//
#include <hip/hip_runtime.h>
#include <hip/hip_bf16.h>

// Problem constants
#define BATCH 2
#define GRP   2
#define NBG   4            // BATCH*GRP
#define CINCH 192          // input channels
#define OG    192          // output channels per group
#define HWDIM 48
#define LPIX  2304         // 48*48
#define KTAP  25           // 5x5
#define IDIM  4800         // CINCH*KTAP
#define NCHUNK 150         // IDIM/32
#define KSPLIT 5           // one kernel row (5 taps) per split
#define XPAD  24576        // 128 l-rows * 192 c of padding each side of g_xt

typedef __attribute__((ext_vector_type(4))) float  float4v;
typedef __attribute__((ext_vector_type(8))) short  short8;

// Static device scratch
// A, fragment-major: [bg][t][otile(3)][i(4)][lane(64)][e(8)] bf16 (per (bg,t): 6144 shorts)
__device__ __align__(16) unsigned short g_wa[(size_t)NBG * NCHUNK * 6144];
__device__ __align__(16) unsigned short g_xt[XPAD + BATCH * LPIX * CINCH + XPAD]; // [b][l][c] bf16, padded
__device__ unsigned long long g_m64[NBG * LPIX];   // 50 mask bits per (bg,l)

__device__ __forceinline__ unsigned short f2bf(float f) {
  union { float f; unsigned int u; } un; un.f = f;
  unsigned int u = un.u;
  return (unsigned short)((u + 0x7fffu + ((u >> 16) & 1u)) >> 16);  // RNE
}

// ---------------------------------------------------------------------------
// ONE prep dispatch, block ranges:
//  [0,216)      transpose+cvt x -> g_xt
//  [216,984)    reorder dkw -> g_wa (fragment-major)
//  [984,1176)   mask bits -> g_m64
//  [1176,1200)  zero g_xt pads
//  [1200,2928)  zero out
__global__ __launch_bounds__(256) void prep(
    const float* __restrict__ x, const int* __restrict__ tg,
    const float* __restrict__ dkw, float* __restrict__ out) {
  __shared__ __align__(16) unsigned char smem[19200];
  const int bx = blockIdx.x, tid = threadIdx.x;

  if (bx < 216) {  // ---- transpose: 64c x 64l tiles via LDS (stride 68)
    unsigned short* tile = (unsigned short*)smem;
    const int c0 = (bx % 3) * 64;
    const int l0 = ((bx / 3) % 36) * 64;
    const int b  = bx / 108;
    #pragma unroll
    for (int it = 0; it < 4; ++it) {
      const int idx = it * 256 + tid;
      const int cl = idx >> 4, lq = idx & 15;
      const float4 v = reinterpret_cast<const float4*>(
          x + ((size_t)b * CINCH + c0 + cl) * LPIX + l0)[lq];
      unsigned short* tp = &tile[cl * 68 + lq * 4];
      tp[0] = f2bf(v.x); tp[1] = f2bf(v.y); tp[2] = f2bf(v.z); tp[3] = f2bf(v.w);
    }
    __syncthreads();
    unsigned short* dst = g_xt + XPAD + ((size_t)b * LPIX) * CINCH;
    #pragma unroll
    for (int it = 0; it < 2; ++it) {
      const int idx = it * 256 + tid;
      const int c8 = idx & 7, ll = idx >> 3;
      unsigned short pk[8];
      #pragma unroll
      for (int e = 0; e < 8; ++e) pk[e] = tile[(c8 * 8 + e) * 68 + ll];
      *reinterpret_cast<uint4*>(dst + (size_t)(l0 + ll) * CINCH + c0 + c8 * 8) =
          *reinterpret_cast<const uint4*>(pk);
    }
  } else if (bx < 984) {  // ---- weight reorder, fragment-major
    float* row = (float*)smem;                 // 4800 floats
    const int blk = bx - 216;                  // bg*192 + o
    const int bg = blk / OG, o = blk % OG;
    const float* src = dkw + (size_t)blk * IDIM;
    for (int i = tid; i < IDIM / 4; i += 256)
      reinterpret_cast<float4*>(row)[i] = reinterpret_cast<const float4*>(src)[i];
    __syncthreads();
    const int ot = o >> 6, fi = (o >> 4) & 3, m = o & 15;
    for (int idx = tid; idx < 600; idx += 256) {  // (t,q) 16B slots
      const int t = idx >> 2, q = idx & 3;
      const int i0 = t * 32 + q * 8;
      const int kk = i0 / CINCH, c0 = i0 % CINCH;
      unsigned int pk[4];
      #pragma unroll
      for (int e = 0; e < 4; ++e) {
        const unsigned lo = f2bf(row[(c0 + 2 * e) * KTAP + kk]);
        const unsigned hi = f2bf(row[(c0 + 2 * e + 1) * KTAP + kk]);
        pk[e] = lo | (hi << 16);
      }
      *reinterpret_cast<uint4*>(
          &g_wa[((size_t)bg * NCHUNK + t) * 6144 + ot * 2048 + fi * 512 +
                (q * 16 + m) * 8]) = *reinterpret_cast<const uint4*>(pk);
    }
  } else if (bx < 1176) {  // ---- mask bits
    const int blk = bx - 984;                  // bg*48 + h
    const int bg = blk / HWDIM, h = blk % HWDIM;
    const int b = bg >> 1, g = bg & 1;
    int* tgs = (int*)smem;                     // [2][5][48]
    for (int i = tid; i < 480; i += 256) {
      const int g2 = i / 240, r5 = (i / 48) % 5, w = i % 48;
      const int hh = h + r5 - 2;
      tgs[i] = (hh >= 0 && hh < HWDIM)
                   ? tg[((b * GRP + g2) * HWDIM + hh) * HWDIM + w]
                   : 0x7fffffff;
    }
    __syncthreads();
    if (tid < HWDIM) {
      const int w = tid;
      const int center = tgs[g * 240 + 96 + w];
      unsigned long long bits = 0ull;
      #pragma unroll
      for (int g2 = 0; g2 < GRP; ++g2)
        #pragma unroll
        for (int kk = 0; kk < KTAP; ++kk) {
          const int ww = w + kk % 5 - 2;
          if (ww >= 0 && ww < HWDIM && tgs[g2 * 240 + (kk / 5) * 48 + ww] < center)
            bits |= 1ull << (g2 * KTAP + kk);
        }
      g_m64[bg * LPIX + h * HWDIM + w] = bits;
    }
  } else if (bx < 1200) {  // ---- zero g_xt pads (2 x 48 KiB)
    const int idx = (bx - 1176) * 256 + tid;   // 0..6143, 16B each
    uint4 z; z.x = z.y = z.z = z.w = 0u;
    if (idx < 3072)
      reinterpret_cast<uint4*>(g_xt)[idx] = z;
    else
      reinterpret_cast<uint4*>(g_xt + XPAD + (size_t)BATCH * LPIX * CINCH)[idx - 3072] = z;
  } else {  // ---- zero out (1728 blocks x 4 KiB = 7.08 MB)
    const int idx = (bx - 1200) * 256 + tid;
    uint4 z; z.x = z.y = z.z = z.w = 0u;
    reinterpret_cast<uint4*>(out)[idx] = z;
  }
}

// ---------------------------------------------------------------------------
// GEMM: block = o64 x l128, 2 waves (wave tile o64 x l64, 4x4 16x16x32 MFMA).
// Per c-chunk ci: stage x window rows [wl0, wl0+131] (64B c-slice) into LDS
// (XOR-swizzled, double-buffered); 5 taps read row = l_local + kt from LDS;
// masked lanes read a zeroed LDS line. A frags load fragment-major from
// global (coalesced, L1-hot). K-split over kernel rows; atomicAdd epilogue.
__global__ __launch_bounds__(128, 2) void gemm_masked(
    const float* __restrict__ dkb, float* __restrict__ out) {
  __shared__ __align__(16) unsigned char sB[16960];  // 2 x 8448 + 64 zero line

  const int ltile = blockIdx.x;              // 0..17 (l-tile of 128)
  const int otile = blockIdx.y;              // 0..2
  const int bg    = blockIdx.z & 3;
  const int ks    = blockIdx.z >> 2;         // kernel row 0..4
  const int b     = bg >> 1;
  const int lbase = ltile * 128, obase = otile * 64;
  const int tid = threadIdx.x, lane = tid & 63, wv = tid >> 6;
  const int q = lane >> 4, m16 = lane & 15;

  // staged window: global l = wl0 + row, row 0..131
  const int wl0 = lbase + (ks - 2) * HWDIM - 2;
  const unsigned short* xwin =
      g_xt + XPAD + (ptrdiff_t)(b * LPIX + wl0) * CINCH;

  // per-lane masks and l-locals for the 4 B fragments
  unsigned bl[4], bh[4];
  int lloc[4];
  #pragma unroll
  for (int j = 0; j < 4; ++j) {
    lloc[j] = wv * 64 + j * 16 + m16;
    const unsigned long long bits = g_m64[bg * LPIX + lbase + lloc[j]];
    bl[j] = (unsigned)(bits & 0x1ffffffull);
    bh[j] = (unsigned)(bits >> KTAP) & 0x1ffffffu;
  }

  // A base (fragment-major): offset(bg,t,ot,i,lane) = (bg*150+t)*6144 + ot*2048 + i*512 + lane*8
  const unsigned short* abase =
      g_wa + (size_t)bg * NCHUNK * 6144 + otile * 2048 + lane * 8;

  float4v acc[4][4];
  #pragma unroll
  for (int i = 0; i < 4; ++i)
    #pragma unroll
    for (int j = 0; j < 4; ++j) acc[i][j] = (float4v)(0.0f);

  // zero line at byte 16896
  if (tid < 4) {
    uint4 z; z.x = z.y = z.z = z.w = 0u;
    *reinterpret_cast<uint4*>(sB + 16896 + tid * 16) = z;
  }

  // staging slot for this thread: 5 passes x (row, s)
  int srow[5], ss[5];
  #pragma unroll
  for (int p = 0; p < 5; ++p) {
    const int idx = p * 128 + tid;
    srow[p] = (idx >> 2) > 131 ? 131 : (idx >> 2);
    ss[p] = idx & 3;
  }

  // prefetch ci=0
  uint4 sv[5];
  #pragma unroll
  for (int p = 0; p < 5; ++p)
    sv[p] = *reinterpret_cast<const uint4*>(xwin + srow[p] * CINCH + ss[p] * 8);

  #pragma unroll
  for (int ci = 0; ci < 6; ++ci) {
    const unsigned bufoff = (ci & 1) * 8448;
    // write staged regs into LDS (swizzled)
    #pragma unroll
    for (int p = 0; p < 5; ++p)
      *reinterpret_cast<uint4*>(
          sB + bufoff + srow[p] * 64 + ((ss[p] ^ (srow[p] & 3)) << 4)) = sv[p];
    __syncthreads();

    // prefetch next ci (drained at the end barrier, covered by compute)
    if (ci < 5) {
      #pragma unroll
      for (int p = 0; p < 5; ++p)
        sv[p] = *reinterpret_cast<const uint4*>(
            xwin + srow[p] * CINCH + (ci + 1) * 32 + ss[p] * 8);
    }

    const unsigned zoff = 16896 + (q << 4);
    #pragma unroll
    for (int kt = 0; kt < 5; ++kt) {
      const int kk = ks * 5 + kt;
      const int t = kk * 6 + ci;
      short8 Af[4];
      #pragma unroll
      for (int i = 0; i < 4; ++i)
        Af[i] = *reinterpret_cast<const short8*>(abase + (size_t)t * 6144 + i * 512);
      short8 Bf[4];
      #pragma unroll
      for (int j = 0; j < 4; ++j) {
        const unsigned bsel = (ci >= 3) ? bh[j] : bl[j];
        const int r = lloc[j] + kt;
        const unsigned roff = bufoff + (r << 6) + (((unsigned)(q ^ (r & 3))) << 4);
        const unsigned off = ((bsel >> kk) & 1u) ? roff : zoff;
        Bf[j] = *reinterpret_cast<const short8*>(sB + off);
      }
      #pragma unroll
      for (int i = 0; i < 4; ++i)
        #pragma unroll
        for (int j = 0; j < 4; ++j)
          acc[i][j] = __builtin_amdgcn_mfma_f32_16x16x32_bf16(Af[i], Bf[j],
                                                              acc[i][j], 0, 0, 0);
    }
    __syncthreads();
  }

  // Epilogue: C/D layout col = lane&15, row = q*4 + reg. Bias added by ks==0.
  #pragma unroll
  for (int i = 0; i < 4; ++i) {
    const int og = obase + i * 16 + q * 4;
    #pragma unroll
    for (int j = 0; j < 4; ++j) {
      const int cl = lbase + lloc[j];
      #pragma unroll
      for (int r = 0; r < 4; ++r) {
        float v = acc[i][j][r];
        if (ks == 0) v += dkb[bg * OG + og + r];
        atomicAdd(&out[(size_t)(bg * OG + og + r) * LPIX + cl], v);
      }
    }
  }
}

// ---------------------------------------------------------------------------
extern "C" void kernel_launch(void* const* d_in, const int* in_sizes, int n_in,
                              void* d_out, int out_size, void* d_ws, size_t ws_size,
                              hipStream_t stream) {
  const float* x   = (const float*)d_in[0];
  const int*   tg  = (const int*)d_in[1];
  const float* dkw = (const float*)d_in[2];
  const float* dkb = (const float*)d_in[3];
  float* out = (float*)d_out;

  prep<<<dim3(2928), 256, 0, stream>>>(x, tg, dkw, out);
  gemm_masked<<<dim3(18, 3, NBG * KSPLIT), 128, 0, stream>>>(dkb, out);
}

// Round 6
// 128.067 us; speedup vs baseline: 1.2578x; 1.1911x over previous
//
#include <hip/hip_runtime.h>
#include <hip/hip_bf16.h>

// Problem constants
#define BATCH 2
#define GRP   2
#define NBG   4            // BATCH*GRP
#define CINCH 192          // input channels
#define OG    192          // output channels per group
#define HWDIM 48
#define LPIX  2304         // 48*48
#define KTAP  25           // 5x5
#define IDIM  4800         // CINCH*KTAP
#define NCHUNK 150         // IDIM/32
#define KSPLIT 5           // one kernel row (5 taps) per split
#define XPAD  24576        // 128 l-rows * 192 c of padding each side of g_xt
#define OUTEL (NBG * OG * LPIX)   // 1769472

typedef __attribute__((ext_vector_type(4))) float  float4v;
typedef __attribute__((ext_vector_type(8))) short  short8;

// Static device scratch
// A, fragment-major: [bg][t][otile(3)][i(4)][lane(64)][e(8)] bf16
__device__ __align__(16) unsigned short g_wa[(size_t)NBG * NCHUNK * 6144];
__device__ __align__(16) unsigned short g_xt[XPAD + BATCH * LPIX * CINCH + XPAD]; // [b][l][c] bf16, padded
__device__ unsigned long long g_m64[NBG * LPIX];   // 50 mask bits per (bg,l)
__device__ __align__(16) float g_part[(size_t)KSPLIT * OUTEL];  // K-split partials

__device__ __forceinline__ unsigned short f2bf(float f) {
  union { float f; unsigned int u; } un; un.f = f;
  unsigned int u = un.u;
  return (unsigned short)((u + 0x7fffu + ((u >> 16) & 1u)) >> 16);  // RNE
}

// ---------------------------------------------------------------------------
// ONE prep dispatch, block ranges:
//  [0,216)      transpose+cvt x -> g_xt
//  [216,984)    reorder dkw -> g_wa (fragment-major)
//  [984,1176)   mask bits -> g_m64
//  [1176,1200)  zero g_xt pads
__global__ __launch_bounds__(256) void prep(
    const float* __restrict__ x, const int* __restrict__ tg,
    const float* __restrict__ dkw) {
  __shared__ __align__(16) unsigned char smem[19200];
  const int bx = blockIdx.x, tid = threadIdx.x;

  if (bx < 216) {  // ---- transpose: 64c x 64l tiles via LDS (stride 68)
    unsigned short* tile = (unsigned short*)smem;
    const int c0 = (bx % 3) * 64;
    const int l0 = ((bx / 3) % 36) * 64;
    const int b  = bx / 108;
    #pragma unroll
    for (int it = 0; it < 4; ++it) {
      const int idx = it * 256 + tid;
      const int cl = idx >> 4, lq = idx & 15;
      const float4 v = reinterpret_cast<const float4*>(
          x + ((size_t)b * CINCH + c0 + cl) * LPIX + l0)[lq];
      unsigned short* tp = &tile[cl * 68 + lq * 4];
      tp[0] = f2bf(v.x); tp[1] = f2bf(v.y); tp[2] = f2bf(v.z); tp[3] = f2bf(v.w);
    }
    __syncthreads();
    unsigned short* dst = g_xt + XPAD + ((size_t)b * LPIX) * CINCH;
    #pragma unroll
    for (int it = 0; it < 2; ++it) {
      const int idx = it * 256 + tid;
      const int c8 = idx & 7, ll = idx >> 3;
      unsigned short pk[8];
      #pragma unroll
      for (int e = 0; e < 8; ++e) pk[e] = tile[(c8 * 8 + e) * 68 + ll];
      *reinterpret_cast<uint4*>(dst + (size_t)(l0 + ll) * CINCH + c0 + c8 * 8) =
          *reinterpret_cast<const uint4*>(pk);
    }
  } else if (bx < 984) {  // ---- weight reorder, fragment-major
    float* row = (float*)smem;                 // 4800 floats
    const int blk = bx - 216;                  // bg*192 + o
    const int bg = blk / OG, o = blk % OG;
    const float* src = dkw + (size_t)blk * IDIM;
    for (int i = tid; i < IDIM / 4; i += 256)
      reinterpret_cast<float4*>(row)[i] = reinterpret_cast<const float4*>(src)[i];
    __syncthreads();
    const int ot = o >> 6, fi = (o >> 4) & 3, m = o & 15;
    for (int idx = tid; idx < 600; idx += 256) {  // (t,q) 16B slots
      const int t = idx >> 2, q = idx & 3;
      const int i0 = t * 32 + q * 8;
      const int kk = i0 / CINCH, c0 = i0 % CINCH;
      unsigned int pk[4];
      #pragma unroll
      for (int e = 0; e < 4; ++e) {
        const unsigned lo = f2bf(row[(c0 + 2 * e) * KTAP + kk]);
        const unsigned hi = f2bf(row[(c0 + 2 * e + 1) * KTAP + kk]);
        pk[e] = lo | (hi << 16);
      }
      *reinterpret_cast<uint4*>(
          &g_wa[((size_t)bg * NCHUNK + t) * 6144 + ot * 2048 + fi * 512 +
                (q * 16 + m) * 8]) = *reinterpret_cast<const uint4*>(pk);
    }
  } else if (bx < 1176) {  // ---- mask bits
    const int blk = bx - 984;                  // bg*48 + h
    const int bg = blk / HWDIM, h = blk % HWDIM;
    const int b = bg >> 1, g = bg & 1;
    int* tgs = (int*)smem;                     // [2][5][48]
    for (int i = tid; i < 480; i += 256) {
      const int g2 = i / 240, r5 = (i / 48) % 5, w = i % 48;
      const int hh = h + r5 - 2;
      tgs[i] = (hh >= 0 && hh < HWDIM)
                   ? tg[((b * GRP + g2) * HWDIM + hh) * HWDIM + w]
                   : 0x7fffffff;
    }
    __syncthreads();
    if (tid < HWDIM) {
      const int w = tid;
      const int center = tgs[g * 240 + 96 + w];
      unsigned long long bits = 0ull;
      #pragma unroll
      for (int g2 = 0; g2 < GRP; ++g2)
        #pragma unroll
        for (int kk = 0; kk < KTAP; ++kk) {
          const int ww = w + kk % 5 - 2;
          if (ww >= 0 && ww < HWDIM && tgs[g2 * 240 + (kk / 5) * 48 + ww] < center)
            bits |= 1ull << (g2 * KTAP + kk);
        }
      g_m64[bg * LPIX + h * HWDIM + w] = bits;
    }
  } else {  // ---- zero g_xt pads (2 x 48 KiB)
    const int idx = (bx - 1176) * 256 + tid;   // 0..6143, 16B each
    uint4 z; z.x = z.y = z.z = z.w = 0u;
    if (idx < 3072)
      reinterpret_cast<uint4*>(g_xt)[idx] = z;
    else
      reinterpret_cast<uint4*>(g_xt + XPAD + (size_t)BATCH * LPIX * CINCH)[idx - 3072] = z;
  }
}

// ---------------------------------------------------------------------------
// GEMM: barrier-free, LDS-free. Block = 4 waves, tile o64 x l128; wave tile
// o64 x l32 = 4x2 mfma_f32_16x16x32_bf16. A frags fragment-major from global
// (coalesced, L1-hot, shared by waves). B frags direct from g_xt (16-line
// gather); masked lanes redirect to zeroed pad page (branchless address
// cndmask). K-split over kernel rows; PLAIN dword stores to g_part
// (device symbol referenced directly — NOT passed from host).
__global__ __launch_bounds__(256, 4) void gemm_masked() {
  const int ltile = blockIdx.x;              // 0..17 (l-tile of 128)
  const int otile = blockIdx.y;              // 0..2
  const int bg    = blockIdx.z & 3;
  const int ks    = blockIdx.z >> 2;         // kernel row 0..4
  const int b     = bg >> 1;
  const int lbase = ltile * 128, obase = otile * 64;
  const int tid = threadIdx.x, lane = tid & 63, wv = tid >> 6;
  const int q = lane >> 4, m16 = lane & 15;

  const unsigned short* zp = g_xt + q * 8;   // zeroed front pad line

  unsigned bl[2], bh[2];
  const unsigned short* xbase[2];
  #pragma unroll
  for (int j = 0; j < 2; ++j) {
    const int lj = lbase + wv * 32 + j * 16 + m16;
    const unsigned long long bits = g_m64[bg * LPIX + lj];
    bl[j] = (unsigned)(bits & 0x1ffffffull);
    bh[j] = (unsigned)(bits >> KTAP) & 0x1ffffffu;
    // row offset for (ks, kt=0): l + (ks-2)*48 - 2; per tap add CINCH
    xbase[j] = g_xt + XPAD +
               (ptrdiff_t)(b * LPIX + lj + (ks - 2) * HWDIM - 2) * CINCH + q * 8;
  }

  // A base: offset(bg,t,ot,i,lane) = (bg*150+t)*6144 + ot*2048 + i*512 + lane*8
  const unsigned short* abase =
      g_wa + ((size_t)bg * NCHUNK + ks * 30) * 6144 + otile * 2048 + lane * 8;

  float4v acc[4][2];
  #pragma unroll
  for (int i = 0; i < 4; ++i)
    #pragma unroll
    for (int j = 0; j < 2; ++j) acc[i][j] = (float4v)(0.0f);

  #pragma unroll
  for (int tt = 0; tt < 30; ++tt) {
    const int kt = tt / 6, ci = tt % 6;      // compile-time (full unroll)
    const int kk = ks * KSPLIT + kt;
    const int imm = kt * CINCH + ci * 32;
    short8 Af[4];
    #pragma unroll
    for (int i = 0; i < 4; ++i)
      Af[i] = *reinterpret_cast<const short8*>(abase + (size_t)tt * 6144 + i * 512);
    short8 Bf[2];
    #pragma unroll
    for (int j = 0; j < 2; ++j) {
      const unsigned bsel = (ci >= 3) ? bh[j] : bl[j];
      const unsigned short* p = ((bsel >> kk) & 1u) ? (xbase[j] + imm) : zp;
      Bf[j] = *reinterpret_cast<const short8*>(p);
    }
    #pragma unroll
    for (int i = 0; i < 4; ++i)
      #pragma unroll
      for (int j = 0; j < 2; ++j)
        acc[i][j] = __builtin_amdgcn_mfma_f32_16x16x32_bf16(Af[i], Bf[j],
                                                            acc[i][j], 0, 0, 0);
  }

  // Epilogue: plain stores to g_part[ks][bg][o][l]. C/D: col=lane&15, row=q*4+r.
  float* pb = g_part + (size_t)ks * OUTEL + (size_t)bg * OG * LPIX;
  #pragma unroll
  for (int i = 0; i < 4; ++i) {
    const int og = obase + i * 16 + q * 4;
    #pragma unroll
    for (int j = 0; j < 2; ++j) {
      const int cl = lbase + wv * 32 + j * 16 + m16;
      #pragma unroll
      for (int r = 0; r < 4; ++r)
        pb[(size_t)(og + r) * LPIX + cl] = acc[i][j][r];
    }
  }
}

// ---------------------------------------------------------------------------
// Reduce: out = sum_ks g_part[ks] + bias. One float4 per thread.
__global__ __launch_bounds__(256) void reduce_part(
    const float* __restrict__ dkb, float* __restrict__ out) {
  const int t4 = blockIdx.x * 256 + threadIdx.x;   // 0..442367
  const int e0 = t4 * 4;
  const int row = e0 / LPIX;                       // bg*192 + o
  const float bias = dkb[row];
  float4 s = reinterpret_cast<const float4*>(g_part)[t4];
  #pragma unroll
  for (int ks = 1; ks < KSPLIT; ++ks) {
    const float4 p =
        reinterpret_cast<const float4*>(g_part + (size_t)ks * OUTEL)[t4];
    s.x += p.x; s.y += p.y; s.z += p.z; s.w += p.w;
  }
  s.x += bias; s.y += bias; s.z += bias; s.w += bias;
  reinterpret_cast<float4*>(out)[t4] = s;
}

// ---------------------------------------------------------------------------
extern "C" void kernel_launch(void* const* d_in, const int* in_sizes, int n_in,
                              void* d_out, int out_size, void* d_ws, size_t ws_size,
                              hipStream_t stream) {
  const float* x   = (const float*)d_in[0];
  const int*   tg  = (const int*)d_in[1];
  const float* dkw = (const float*)d_in[2];
  const float* dkb = (const float*)d_in[3];
  float* out = (float*)d_out;

  prep<<<dim3(1200), 256, 0, stream>>>(x, tg, dkw);
  gemm_masked<<<dim3(18, 3, NBG * KSPLIT), 256, 0, stream>>>();
  reduce_part<<<dim3(OUTEL / 1024), 256, 0, stream>>>(dkb, out);
}

// Round 7
// 123.280 us; speedup vs baseline: 1.3066x; 1.0388x over previous
//
#include <hip/hip_runtime.h>
#include <hip/hip_bf16.h>

// Problem constants
#define BATCH 2
#define GRP   2
#define NBG   4            // BATCH*GRP
#define CINCH 192          // input channels
#define OG    192          // output channels per group
#define HWDIM 48
#define LPIX  2304         // 48*48
#define KTAP  25           // 5x5
#define IDIM  4800         // CINCH*KTAP
#define NCHUNK 150         // IDIM/32
#define KSPLIT 5           // one kernel row (5 taps) per split
#define XPAD  24576        // 128 l-rows * 192 c of padding each side of g_xt
#define OUTEL (NBG * OG * LPIX)   // 1769472

typedef __attribute__((ext_vector_type(4))) float  float4v;
typedef __attribute__((ext_vector_type(8))) short  short8;

// Static device scratch
// A, fragment-major: [bg][t][ot(3)][i(4)][m(16)][q(4)][e(8)] bf16
//   slot offset (shorts) = i*512 + (m*4+q)*8  — per (o,t) contiguous 64 B
__device__ __align__(16) unsigned short g_wa[(size_t)NBG * NCHUNK * 6144];
__device__ __align__(16) unsigned short g_xt[XPAD + BATCH * LPIX * CINCH + XPAD]; // [b][l][c] bf16, padded
__device__ unsigned long long g_m64[NBG * LPIX];   // 50 mask bits per (bg,l)
__device__ __align__(16) unsigned short g_part[(size_t)KSPLIT * OUTEL];  // bf16 K-split partials

__device__ __forceinline__ unsigned short f2bf(float f) {
  union { float f; unsigned int u; } un; un.f = f;
  unsigned int u = un.u;
  return (unsigned short)((u + 0x7fffu + ((u >> 16) & 1u)) >> 16);  // RNE
}

// ---------------------------------------------------------------------------
// ONE prep dispatch, block ranges:
//  [0,216)      transpose+cvt x -> g_xt
//  [216,984)    reorder dkw -> g_wa (fragment-major, coalesced 64B stores)
//  [984,1176)   mask bits -> g_m64
//  [1176,1200)  zero g_xt pads
__global__ __launch_bounds__(256) void prep(
    const float* __restrict__ x, const int* __restrict__ tg,
    const float* __restrict__ dkw) {
  __shared__ __align__(16) unsigned char smem[19200];
  const int bx = blockIdx.x, tid = threadIdx.x;

  if (bx < 216) {  // ---- transpose: 64c x 64l tiles via LDS (stride 68)
    unsigned short* tile = (unsigned short*)smem;
    const int c0 = (bx % 3) * 64;
    const int l0 = ((bx / 3) % 36) * 64;
    const int b  = bx / 108;
    #pragma unroll
    for (int it = 0; it < 4; ++it) {
      const int idx = it * 256 + tid;
      const int cl = idx >> 4, lq = idx & 15;
      const float4 v = reinterpret_cast<const float4*>(
          x + ((size_t)b * CINCH + c0 + cl) * LPIX + l0)[lq];
      unsigned short* tp = &tile[cl * 68 + lq * 4];
      tp[0] = f2bf(v.x); tp[1] = f2bf(v.y); tp[2] = f2bf(v.z); tp[3] = f2bf(v.w);
    }
    __syncthreads();
    unsigned short* dst = g_xt + XPAD + ((size_t)b * LPIX) * CINCH;
    #pragma unroll
    for (int it = 0; it < 2; ++it) {
      const int idx = it * 256 + tid;
      const int c8 = idx & 7, ll = idx >> 3;
      unsigned short pk[8];
      #pragma unroll
      for (int e = 0; e < 8; ++e) pk[e] = tile[(c8 * 8 + e) * 68 + ll];
      *reinterpret_cast<uint4*>(dst + (size_t)(l0 + ll) * CINCH + c0 + c8 * 8) =
          *reinterpret_cast<const uint4*>(pk);
    }
  } else if (bx < 984) {  // ---- weight reorder, fragment-major
    float* row = (float*)smem;                 // 4800 floats
    const int blk = bx - 216;                  // bg*192 + o
    const int bg = blk / OG, o = blk % OG;
    const float* src = dkw + (size_t)blk * IDIM;
    for (int i = tid; i < IDIM / 4; i += 256)
      reinterpret_cast<float4*>(row)[i] = reinterpret_cast<const float4*>(src)[i];
    __syncthreads();
    const int ot = o >> 6, fi = (o >> 4) & 3, m = o & 15;
    unsigned short* wbase =
        g_wa + (size_t)bg * NCHUNK * 6144 + ot * 2048 + fi * 512 + m * 32;
    for (int t = tid; t < NCHUNK; t += 256) {  // one 64B granule per t
      const int kk = t / 6, c0 = (t % 6) * 32;
      unsigned int pk[16];
      #pragma unroll
      for (int q = 0; q < 4; ++q)
        #pragma unroll
        for (int e = 0; e < 4; ++e) {
          const int c = c0 + q * 8 + e * 2;
          const unsigned lo = f2bf(row[c * KTAP + kk]);
          const unsigned hi = f2bf(row[(c + 1) * KTAP + kk]);
          pk[q * 4 + e] = lo | (hi << 16);
        }
      unsigned short* dst = wbase + (size_t)t * 6144;
      #pragma unroll
      for (int q = 0; q < 4; ++q)
        reinterpret_cast<uint4*>(dst)[q] = *reinterpret_cast<const uint4*>(pk + q * 4);
    }
  } else if (bx < 1176) {  // ---- mask bits
    const int blk = bx - 984;                  // bg*48 + h
    const int bg = blk / HWDIM, h = blk % HWDIM;
    const int b = bg >> 1, g = bg & 1;
    int* tgs = (int*)smem;                     // [2][5][48]
    for (int i = tid; i < 480; i += 256) {
      const int g2 = i / 240, r5 = (i / 48) % 5, w = i % 48;
      const int hh = h + r5 - 2;
      tgs[i] = (hh >= 0 && hh < HWDIM)
                   ? tg[((b * GRP + g2) * HWDIM + hh) * HWDIM + w]
                   : 0x7fffffff;
    }
    __syncthreads();
    if (tid < HWDIM) {
      const int w = tid;
      const int center = tgs[g * 240 + 96 + w];
      unsigned long long bits = 0ull;
      #pragma unroll
      for (int g2 = 0; g2 < GRP; ++g2)
        #pragma unroll
        for (int kk = 0; kk < KTAP; ++kk) {
          const int ww = w + kk % 5 - 2;
          if (ww >= 0 && ww < HWDIM && tgs[g2 * 240 + (kk / 5) * 48 + ww] < center)
            bits |= 1ull << (g2 * KTAP + kk);
        }
      g_m64[bg * LPIX + h * HWDIM + w] = bits;
    }
  } else {  // ---- zero g_xt pads (2 x 48 KiB)
    const int idx = (bx - 1176) * 256 + tid;   // 0..6143, 16B each
    uint4 z; z.x = z.y = z.z = z.w = 0u;
    if (idx < 3072)
      reinterpret_cast<uint4*>(g_xt)[idx] = z;
    else
      reinterpret_cast<uint4*>(g_xt + XPAD + (size_t)BATCH * LPIX * CINCH)[idx - 3072] = z;
  }
}

// ---------------------------------------------------------------------------
// GEMM: barrier-free, LDS-free. Block = 2 waves (128 thr), tile o64 x l128;
// wave tile o64 x l64 = 4x4 mfma_f32_16x16x32_bf16 -> 16 MFMA per 8 loads.
// A frags fragment-major from global (coalesced 1KB/wave, L1-hot). B frags
// direct from g_xt; masked lanes redirect to zeroed pad (branchless).
// K-split over kernel rows; bf16 partial stores to g_part (no atomics).
__global__ __launch_bounds__(128, 2) void gemm_masked() {
  const int ltile = blockIdx.x;              // 0..17 (l-tile of 128)
  const int otile = blockIdx.y;              // 0..2
  const int bg    = blockIdx.z & 3;
  const int ks    = blockIdx.z >> 2;         // kernel row 0..4
  const int b     = bg >> 1;
  const int lbase = ltile * 128, obase = otile * 64;
  const int tid = threadIdx.x, lane = tid & 63, wv = tid >> 6;
  const int q = lane >> 4, m16 = lane & 15;

  const unsigned short* zp = g_xt + q * 8;   // zeroed front pad line

  unsigned bl[4], bh[4];
  const unsigned short* xbase[4];
  #pragma unroll
  for (int j = 0; j < 4; ++j) {
    const int lj = lbase + wv * 64 + j * 16 + m16;
    const unsigned long long bits = g_m64[bg * LPIX + lj];
    bl[j] = (unsigned)(bits & 0x1ffffffull);
    bh[j] = (unsigned)(bits >> KTAP) & 0x1ffffffu;
    // row offset for (ks, kt=0): l + (ks-2)*48 - 2; per tap add CINCH
    xbase[j] = g_xt + XPAD +
               (ptrdiff_t)(b * LPIX + lj + (ks - 2) * HWDIM - 2) * CINCH + q * 8;
  }

  // A base: (bg,t) blob + ot*2048 + (m*4+q)*8 ; frag i at +i*512
  const unsigned short* abase =
      g_wa + ((size_t)bg * NCHUNK + ks * 30) * 6144 + otile * 2048 +
      (m16 * 4 + q) * 8;

  float4v acc[4][4];
  #pragma unroll
  for (int i = 0; i < 4; ++i)
    #pragma unroll
    for (int j = 0; j < 4; ++j) acc[i][j] = (float4v)(0.0f);

  #pragma unroll
  for (int tt = 0; tt < 30; ++tt) {
    const int kt = tt / 6, ci = tt % 6;      // compile-time (full unroll)
    const int kk = ks * KSPLIT + kt;
    const int imm = kt * CINCH + ci * 32;
    short8 Af[4];
    #pragma unroll
    for (int i = 0; i < 4; ++i)
      Af[i] = *reinterpret_cast<const short8*>(abase + (size_t)tt * 6144 + i * 512);
    short8 Bf[4];
    #pragma unroll
    for (int j = 0; j < 4; ++j) {
      const unsigned bsel = (ci >= 3) ? bh[j] : bl[j];
      const unsigned short* p = ((bsel >> kk) & 1u) ? (xbase[j] + imm) : zp;
      Bf[j] = *reinterpret_cast<const short8*>(p);
    }
    #pragma unroll
    for (int i = 0; i < 4; ++i)
      #pragma unroll
      for (int j = 0; j < 4; ++j)
        acc[i][j] = __builtin_amdgcn_mfma_f32_16x16x32_bf16(Af[i], Bf[j],
                                                            acc[i][j], 0, 0, 0);
  }

  // Epilogue: bf16 partial stores to g_part[ks][bg][o][l].
  // C/D layout: col = lane&15, row = q*4 + r.
  unsigned short* pb = g_part + (size_t)ks * OUTEL + (size_t)bg * OG * LPIX;
  #pragma unroll
  for (int i = 0; i < 4; ++i) {
    const int og = obase + i * 16 + q * 4;
    #pragma unroll
    for (int j = 0; j < 4; ++j) {
      const int cl = lbase + wv * 64 + j * 16 + m16;
      #pragma unroll
      for (int r = 0; r < 4; ++r)
        pb[(size_t)(og + r) * LPIX + cl] = f2bf(acc[i][j][r]);
    }
  }
}

// ---------------------------------------------------------------------------
// Reduce: out = sum_ks bf16(g_part[ks]) + bias. 8 elements per thread.
__global__ __launch_bounds__(256) void reduce_part(
    const float* __restrict__ dkb, float* __restrict__ out) {
  const int t8 = blockIdx.x * 256 + threadIdx.x;   // 0..221183
  const size_t e0 = (size_t)t8 * 8;
  const int row = (int)(e0 / LPIX);                // bg*192 + o (8 els same row)
  const float bias = dkb[row];
  float s[8];
  #pragma unroll
  for (int k = 0; k < 8; ++k) s[k] = bias;
  #pragma unroll
  for (int ks = 0; ks < KSPLIT; ++ks) {
    const uint4 v = *reinterpret_cast<const uint4*>(
        g_part + (size_t)ks * OUTEL + e0);
    const unsigned u[4] = {v.x, v.y, v.z, v.w};
    #pragma unroll
    for (int p = 0; p < 4; ++p) {
      union { unsigned u; float f; } lo, hi;
      lo.u = u[p] << 16;
      hi.u = u[p] & 0xffff0000u;
      s[2 * p]     += lo.f;
      s[2 * p + 1] += hi.f;
    }
  }
  float4 o0, o1;
  o0.x = s[0]; o0.y = s[1]; o0.z = s[2]; o0.w = s[3];
  o1.x = s[4]; o1.y = s[5]; o1.z = s[6]; o1.w = s[7];
  reinterpret_cast<float4*>(out)[t8 * 2]     = o0;
  reinterpret_cast<float4*>(out)[t8 * 2 + 1] = o1;
}

// ---------------------------------------------------------------------------
extern "C" void kernel_launch(void* const* d_in, const int* in_sizes, int n_in,
                              void* d_out, int out_size, void* d_ws, size_t ws_size,
                              hipStream_t stream) {
  const float* x   = (const float*)d_in[0];
  const int*   tg  = (const int*)d_in[1];
  const float* dkw = (const float*)d_in[2];
  const float* dkb = (const float*)d_in[3];
  float* out = (float*)d_out;

  prep<<<dim3(1200), 256, 0, stream>>>(x, tg, dkw);
  gemm_masked<<<dim3(18, 3, NBG * KSPLIT), 128, 0, stream>>>();
  reduce_part<<<dim3(OUTEL / 2048), 256, 0, stream>>>(dkb, out);
}

// Round 8
// 121.620 us; speedup vs baseline: 1.3244x; 1.0137x over previous
//
#include <hip/hip_runtime.h>
#include <hip/hip_bf16.h>

// Problem constants
#define BATCH 2
#define GRP   2
#define NBG   4            // BATCH*GRP
#define CINCH 192          // input channels
#define OG    192          // output channels per group
#define HWDIM 48
#define LPIX  2304         // 48*48
#define KTAP  25           // 5x5
#define IDIM  4800         // CINCH*KTAP
#define NCHUNK 150         // IDIM/32
#define KSPLIT 5           // one kernel row (5 taps) per split
#define XPAD  24576        // 128 l-rows * 192 c of padding each side of g_xt
#define OUTEL (NBG * OG * LPIX)   // 1769472
#define LROW  400          // LDS bytes per staged row (384 data + 16 pad)
#define ZOFF  (132 * LROW) // zero line offset (52800); LDS total 52864 B

typedef __attribute__((ext_vector_type(4))) float  float4v;
typedef __attribute__((ext_vector_type(8))) short  short8;

// Static device scratch
// A, fragment-major: [bg][t][ot(3)][i(4)][m(16)][q(4)][e(8)] bf16
__device__ __align__(16) unsigned short g_wa[(size_t)NBG * NCHUNK * 6144];
__device__ __align__(16) unsigned short g_xt[XPAD + BATCH * LPIX * CINCH + XPAD]; // [b][l][c] bf16, padded
__device__ unsigned long long g_m64[NBG * LPIX];   // 50 mask bits per (bg,l)
__device__ __align__(16) unsigned short g_part[(size_t)KSPLIT * OUTEL];  // bf16 K-split partials

__device__ __forceinline__ unsigned short f2bf(float f) {
  union { float f; unsigned int u; } un; un.f = f;
  unsigned int u = un.u;
  return (unsigned short)((u + 0x7fffu + ((u >> 16) & 1u)) >> 16);  // RNE
}

// ---------------------------------------------------------------------------
// ONE prep dispatch, block ranges:
//  [0,216)      transpose+cvt x -> g_xt
//  [216,984)    reorder dkw -> g_wa (fragment-major, coalesced 64B stores)
//  [984,1176)   mask bits -> g_m64
//  [1176,1200)  zero g_xt pads
__global__ __launch_bounds__(256) void prep(
    const float* __restrict__ x, const int* __restrict__ tg,
    const float* __restrict__ dkw) {
  __shared__ __align__(16) unsigned char smem[19200];
  const int bx = blockIdx.x, tid = threadIdx.x;

  if (bx < 216) {  // ---- transpose: 64c x 64l tiles via LDS (stride 68)
    unsigned short* tile = (unsigned short*)smem;
    const int c0 = (bx % 3) * 64;
    const int l0 = ((bx / 3) % 36) * 64;
    const int b  = bx / 108;
    #pragma unroll
    for (int it = 0; it < 4; ++it) {
      const int idx = it * 256 + tid;
      const int cl = idx >> 4, lq = idx & 15;
      const float4 v = reinterpret_cast<const float4*>(
          x + ((size_t)b * CINCH + c0 + cl) * LPIX + l0)[lq];
      unsigned short* tp = &tile[cl * 68 + lq * 4];
      tp[0] = f2bf(v.x); tp[1] = f2bf(v.y); tp[2] = f2bf(v.z); tp[3] = f2bf(v.w);
    }
    __syncthreads();
    unsigned short* dst = g_xt + XPAD + ((size_t)b * LPIX) * CINCH;
    #pragma unroll
    for (int it = 0; it < 2; ++it) {
      const int idx = it * 256 + tid;
      const int c8 = idx & 7, ll = idx >> 3;
      unsigned short pk[8];
      #pragma unroll
      for (int e = 0; e < 8; ++e) pk[e] = tile[(c8 * 8 + e) * 68 + ll];
      *reinterpret_cast<uint4*>(dst + (size_t)(l0 + ll) * CINCH + c0 + c8 * 8) =
          *reinterpret_cast<const uint4*>(pk);
    }
  } else if (bx < 984) {  // ---- weight reorder, fragment-major
    float* row = (float*)smem;                 // 4800 floats
    const int blk = bx - 216;                  // bg*192 + o
    const int bg = blk / OG, o = blk % OG;
    const float* src = dkw + (size_t)blk * IDIM;
    for (int i = tid; i < IDIM / 4; i += 256)
      reinterpret_cast<float4*>(row)[i] = reinterpret_cast<const float4*>(src)[i];
    __syncthreads();
    const int ot = o >> 6, fi = (o >> 4) & 3, m = o & 15;
    unsigned short* wbase =
        g_wa + (size_t)bg * NCHUNK * 6144 + ot * 2048 + fi * 512 + m * 32;
    for (int t = tid; t < NCHUNK; t += 256) {  // one 64B granule per t
      const int kk = t / 6, c0 = (t % 6) * 32;
      unsigned int pk[16];
      #pragma unroll
      for (int q = 0; q < 4; ++q)
        #pragma unroll
        for (int e = 0; e < 4; ++e) {
          const int c = c0 + q * 8 + e * 2;
          const unsigned lo = f2bf(row[c * KTAP + kk]);
          const unsigned hi = f2bf(row[(c + 1) * KTAP + kk]);
          pk[q * 4 + e] = lo | (hi << 16);
        }
      unsigned short* dst = wbase + (size_t)t * 6144;
      #pragma unroll
      for (int q = 0; q < 4; ++q)
        reinterpret_cast<uint4*>(dst)[q] = *reinterpret_cast<const uint4*>(pk + q * 4);
    }
  } else if (bx < 1176) {  // ---- mask bits
    const int blk = bx - 984;                  // bg*48 + h
    const int bg = blk / HWDIM, h = blk % HWDIM;
    const int b = bg >> 1, g = bg & 1;
    int* tgs = (int*)smem;                     // [2][5][48]
    for (int i = tid; i < 480; i += 256) {
      const int g2 = i / 240, r5 = (i / 48) % 5, w = i % 48;
      const int hh = h + r5 - 2;
      tgs[i] = (hh >= 0 && hh < HWDIM)
                   ? tg[((b * GRP + g2) * HWDIM + hh) * HWDIM + w]
                   : 0x7fffffff;
    }
    __syncthreads();
    if (tid < HWDIM) {
      const int w = tid;
      const int center = tgs[g * 240 + 96 + w];
      unsigned long long bits = 0ull;
      #pragma unroll
      for (int g2 = 0; g2 < GRP; ++g2)
        #pragma unroll
        for (int kk = 0; kk < KTAP; ++kk) {
          const int ww = w + kk % 5 - 2;
          if (ww >= 0 && ww < HWDIM && tgs[g2 * 240 + (kk / 5) * 48 + ww] < center)
            bits |= 1ull << (g2 * KTAP + kk);
        }
      g_m64[bg * LPIX + h * HWDIM + w] = bits;
    }
  } else {  // ---- zero g_xt pads (2 x 48 KiB)
    const int idx = (bx - 1176) * 256 + tid;   // 0..6143, 16B each
    uint4 z; z.x = z.y = z.z = z.w = 0u;
    if (idx < 3072)
      reinterpret_cast<uint4*>(g_xt)[idx] = z;
    else
      reinterpret_cast<uint4*>(g_xt + XPAD + (size_t)BATCH * LPIX * CINCH)[idx - 3072] = z;
  }
}

// ---------------------------------------------------------------------------
// GEMM: B staged in LDS ONCE per block (contiguous 50.7 KB row-window of
// g_xt, rows padded 384->400 B), single barrier, then a fully-unrolled
// 30-chunk loop: A from global (fragment-major, coalesced, affine addrs ->
// deep compiler pipelining), B via ds_read_b128 (masked lanes -> zeroed LDS
// line, broadcast). Block = 2 waves, tile o64 x l128; wave tile o64 x l64 =
// 4x4 mfma_f32_16x16x32_bf16. K-split over kernel rows; bf16 partial stores.
__global__ __launch_bounds__(128, 2) void gemm_masked() {
  __shared__ __align__(16) unsigned char sB[ZOFF + 64];

  const int ltile = blockIdx.x;              // 0..17 (l-tile of 128)
  const int otile = blockIdx.y;              // 0..2
  const int bg    = blockIdx.z & 3;
  const int ks    = blockIdx.z >> 2;         // kernel row 0..4
  const int b     = bg >> 1;
  const int lbase = ltile * 128, obase = otile * 64;
  const int tid = threadIdx.x, lane = tid & 63, wv = tid >> 6;
  const int q = lane >> 4, m16 = lane & 15;

  // ---- stage window rows [wl0, wl0+131] (contiguous in g_xt) into LDS
  const int wl0 = lbase + (ks - 2) * HWDIM - 2;
  const unsigned short* xwin = g_xt + XPAD + (ptrdiff_t)(b * LPIX + wl0) * CINCH;
  #pragma unroll
  for (int it = 0; it < 25; ++it) {          // 132*24 = 3168 granules of 16 B
    const int i = it * 128 + tid;
    if (it < 24 || i < 3168) {
      const int r = i / 24, g = i % 24;      // src is linear: granule i
      *reinterpret_cast<uint4*>(sB + r * LROW + g * 16) =
          *reinterpret_cast<const uint4*>(xwin + i * 8);
    }
  }
  if (tid < 4) {  // zero line
    uint4 z; z.x = z.y = z.z = z.w = 0u;
    *reinterpret_cast<uint4*>(sB + ZOFF + tid * 16) = z;
  }

  // ---- per-fragment masks (pre-shifted by ks*5) and LDS base offsets
  unsigned bls[4], bhs[4], bboff[4];
  #pragma unroll
  for (int j = 0; j < 4; ++j) {
    const int lj = wv * 64 + j * 16 + m16;
    const unsigned long long bits = g_m64[bg * LPIX + lbase + lj];
    bls[j] = ((unsigned)(bits & 0x1ffffffull)) >> (ks * 5);
    bhs[j] = ((unsigned)((bits >> KTAP) & 0x1ffffffull)) >> (ks * 5);
    bboff[j] = lj * LROW + q * 16;
  }
  const unsigned zoff = ZOFF + q * 16;

  // A base: (bg,t) blob + ot*2048 + (m*4+q)*8 ; frag i at +i*512
  const unsigned short* abase =
      g_wa + ((size_t)bg * NCHUNK + ks * 30) * 6144 + otile * 2048 +
      (m16 * 4 + q) * 8;

  float4v acc[4][4];
  #pragma unroll
  for (int i = 0; i < 4; ++i)
    #pragma unroll
    for (int j = 0; j < 4; ++j) acc[i][j] = (float4v)(0.0f);

  __syncthreads();

  #pragma unroll
  for (int tt = 0; tt < 30; ++tt) {
    const int kt = tt / 6, ci = tt % 6;      // compile-time (full unroll)
    short8 Af[4];
    #pragma unroll
    for (int i = 0; i < 4; ++i)
      Af[i] = *reinterpret_cast<const short8*>(abase + (size_t)tt * 6144 + i * 512);
    short8 Bf[4];
    #pragma unroll
    for (int j = 0; j < 4; ++j) {
      const unsigned bit = (((ci >= 3) ? bhs[j] : bls[j]) >> kt) & 1u;
      const unsigned off = bit ? (bboff[j] + kt * LROW + ci * 64) : zoff;
      Bf[j] = *reinterpret_cast<const short8*>(sB + off);
    }
    #pragma unroll
    for (int i = 0; i < 4; ++i)
      #pragma unroll
      for (int j = 0; j < 4; ++j)
        acc[i][j] = __builtin_amdgcn_mfma_f32_16x16x32_bf16(Af[i], Bf[j],
                                                            acc[i][j], 0, 0, 0);
  }

  // Epilogue: bf16 partial stores to g_part[ks][bg][o][l].
  // C/D layout: col = lane&15, row = q*4 + r.
  unsigned short* pb = g_part + (size_t)ks * OUTEL + (size_t)bg * OG * LPIX;
  #pragma unroll
  for (int i = 0; i < 4; ++i) {
    const int og = obase + i * 16 + q * 4;
    #pragma unroll
    for (int j = 0; j < 4; ++j) {
      const int cl = lbase + wv * 64 + j * 16 + m16;
      #pragma unroll
      for (int r = 0; r < 4; ++r)
        pb[(size_t)(og + r) * LPIX + cl] = f2bf(acc[i][j][r]);
    }
  }
}

// ---------------------------------------------------------------------------
// Reduce: out = sum_ks bf16(g_part[ks]) + bias. 8 elements per thread.
__global__ __launch_bounds__(256) void reduce_part(
    const float* __restrict__ dkb, float* __restrict__ out) {
  const int t8 = blockIdx.x * 256 + threadIdx.x;   // 0..221183
  const size_t e0 = (size_t)t8 * 8;
  const int row = (int)(e0 / LPIX);                // bg*192 + o (8 els same row)
  const float bias = dkb[row];
  float s[8];
  #pragma unroll
  for (int k = 0; k < 8; ++k) s[k] = bias;
  #pragma unroll
  for (int ks = 0; ks < KSPLIT; ++ks) {
    const uint4 v = *reinterpret_cast<const uint4*>(
        g_part + (size_t)ks * OUTEL + e0);
    const unsigned u[4] = {v.x, v.y, v.z, v.w};
    #pragma unroll
    for (int p = 0; p < 4; ++p) {
      union { unsigned u; float f; } lo, hi;
      lo.u = u[p] << 16;
      hi.u = u[p] & 0xffff0000u;
      s[2 * p]     += lo.f;
      s[2 * p + 1] += hi.f;
    }
  }
  float4 o0, o1;
  o0.x = s[0]; o0.y = s[1]; o0.z = s[2]; o0.w = s[3];
  o1.x = s[4]; o1.y = s[5]; o1.z = s[6]; o1.w = s[7];
  reinterpret_cast<float4*>(out)[t8 * 2]     = o0;
  reinterpret_cast<float4*>(out)[t8 * 2 + 1] = o1;
}

// ---------------------------------------------------------------------------
extern "C" void kernel_launch(void* const* d_in, const int* in_sizes, int n_in,
                              void* d_out, int out_size, void* d_ws, size_t ws_size,
                              hipStream_t stream) {
  const float* x   = (const float*)d_in[0];
  const int*   tg  = (const int*)d_in[1];
  const float* dkw = (const float*)d_in[2];
  const float* dkb = (const float*)d_in[3];
  float* out = (float*)d_out;

  prep<<<dim3(1200), 256, 0, stream>>>(x, tg, dkw);
  gemm_masked<<<dim3(18, 3, NBG * KSPLIT), 128, 0, stream>>>();
  reduce_part<<<dim3(OUTEL / 2048), 256, 0, stream>>>(dkb, out);
}

// Round 9
// 117.273 us; speedup vs baseline: 1.3735x; 1.0371x over previous
//
#include <hip/hip_runtime.h>
#include <hip/hip_bf16.h>

// Problem constants
#define BATCH 2
#define GRP   2
#define NBG   4            // BATCH*GRP
#define CINCH 192          // input channels
#define OG    192          // output channels per group
#define HWDIM 48
#define LPIX  2304         // 48*48
#define KTAP  25           // 5x5
#define IDIM  4800         // CINCH*KTAP
#define NCHUNK 150         // IDIM/32
#define KSPLIT 5           // one kernel row (5 taps) per split
#define XPAD  24576        // 128 l-rows * 192 c of padding each side of g_xt
#define OUTEL (NBG * OG * LPIX)   // 1769472
#define LROW  400          // LDS bytes per staged row (384 data + 16 pad)
#define ZOFF  (132 * LROW) // zero line offset (52800); LDS total 52864 B

typedef __attribute__((ext_vector_type(4))) float  float4v;
typedef __attribute__((ext_vector_type(8))) short  short8;

// Static device scratch
// A, fragment-major: [bg][t][ot(3)][i(4)][m(16)][q(4)][e(8)] bf16
__device__ __align__(16) unsigned short g_wa[(size_t)NBG * NCHUNK * 6144];
__device__ __align__(16) unsigned short g_xt[XPAD + BATCH * LPIX * CINCH + XPAD]; // [b][l][c] bf16, padded
__device__ unsigned long long g_m64[NBG * LPIX];   // 50 mask bits per (bg,l)
__device__ __align__(16) unsigned short g_part[(size_t)KSPLIT * OUTEL];  // bf16 K-split partials

__device__ __forceinline__ unsigned short f2bf(float f) {
  union { float f; unsigned int u; } un; un.f = f;
  unsigned int u = un.u;
  return (unsigned short)((u + 0x7fffu + ((u >> 16) & 1u)) >> 16);  // RNE
}

// ---------------------------------------------------------------------------
// ONE prep dispatch, block ranges:
//  [0,216)      transpose+cvt x -> g_xt
//  [216,984)    reorder dkw -> g_wa (fragment-major, coalesced 64B stores)
//  [984,1176)   mask bits -> g_m64
//  [1176,1200)  zero g_xt pads
__global__ __launch_bounds__(256) void prep(
    const float* __restrict__ x, const int* __restrict__ tg,
    const float* __restrict__ dkw) {
  __shared__ __align__(16) unsigned char smem[19200];
  const int bx = blockIdx.x, tid = threadIdx.x;

  if (bx < 216) {  // ---- transpose: 64c x 64l tiles via LDS (stride 68)
    unsigned short* tile = (unsigned short*)smem;
    const int c0 = (bx % 3) * 64;
    const int l0 = ((bx / 3) % 36) * 64;
    const int b  = bx / 108;
    #pragma unroll
    for (int it = 0; it < 4; ++it) {
      const int idx = it * 256 + tid;
      const int cl = idx >> 4, lq = idx & 15;
      const float4 v = reinterpret_cast<const float4*>(
          x + ((size_t)b * CINCH + c0 + cl) * LPIX + l0)[lq];
      unsigned short* tp = &tile[cl * 68 + lq * 4];
      tp[0] = f2bf(v.x); tp[1] = f2bf(v.y); tp[2] = f2bf(v.z); tp[3] = f2bf(v.w);
    }
    __syncthreads();
    unsigned short* dst = g_xt + XPAD + ((size_t)b * LPIX) * CINCH;
    #pragma unroll
    for (int it = 0; it < 2; ++it) {
      const int idx = it * 256 + tid;
      const int c8 = idx & 7, ll = idx >> 3;
      unsigned short pk[8];
      #pragma unroll
      for (int e = 0; e < 8; ++e) pk[e] = tile[(c8 * 8 + e) * 68 + ll];
      *reinterpret_cast<uint4*>(dst + (size_t)(l0 + ll) * CINCH + c0 + c8 * 8) =
          *reinterpret_cast<const uint4*>(pk);
    }
  } else if (bx < 984) {  // ---- weight reorder, fragment-major
    float* row = (float*)smem;                 // 4800 floats
    const int blk = bx - 216;                  // bg*192 + o
    const int bg = blk / OG, o = blk % OG;
    const float* src = dkw + (size_t)blk * IDIM;
    for (int i = tid; i < IDIM / 4; i += 256)
      reinterpret_cast<float4*>(row)[i] = reinterpret_cast<const float4*>(src)[i];
    __syncthreads();
    const int ot = o >> 6, fi = (o >> 4) & 3, m = o & 15;
    unsigned short* wbase =
        g_wa + (size_t)bg * NCHUNK * 6144 + ot * 2048 + fi * 512 + m * 32;
    for (int t = tid; t < NCHUNK; t += 256) {  // one 64B granule per t
      const int kk = t / 6, c0 = (t % 6) * 32;
      unsigned int pk[16];
      #pragma unroll
      for (int q = 0; q < 4; ++q)
        #pragma unroll
        for (int e = 0; e < 4; ++e) {
          const int c = c0 + q * 8 + e * 2;
          const unsigned lo = f2bf(row[c * KTAP + kk]);
          const unsigned hi = f2bf(row[(c + 1) * KTAP + kk]);
          pk[q * 4 + e] = lo | (hi << 16);
        }
      unsigned short* dst = wbase + (size_t)t * 6144;
      #pragma unroll
      for (int q = 0; q < 4; ++q)
        reinterpret_cast<uint4*>(dst)[q] = *reinterpret_cast<const uint4*>(pk + q * 4);
    }
  } else if (bx < 1176) {  // ---- mask bits
    const int blk = bx - 984;                  // bg*48 + h
    const int bg = blk / HWDIM, h = blk % HWDIM;
    const int b = bg >> 1, g = bg & 1;
    int* tgs = (int*)smem;                     // [2][5][48]
    for (int i = tid; i < 480; i += 256) {
      const int g2 = i / 240, r5 = (i / 48) % 5, w = i % 48;
      const int hh = h + r5 - 2;
      tgs[i] = (hh >= 0 && hh < HWDIM)
                   ? tg[((b * GRP + g2) * HWDIM + hh) * HWDIM + w]
                   : 0x7fffffff;
    }
    __syncthreads();
    if (tid < HWDIM) {
      const int w = tid;
      const int center = tgs[g * 240 + 96 + w];
      unsigned long long bits = 0ull;
      #pragma unroll
      for (int g2 = 0; g2 < GRP; ++g2)
        #pragma unroll
        for (int kk = 0; kk < KTAP; ++kk) {
          const int ww = w + kk % 5 - 2;
          if (ww >= 0 && ww < HWDIM && tgs[g2 * 240 + (kk / 5) * 48 + ww] < center)
            bits |= 1ull << (g2 * KTAP + kk);
        }
      g_m64[bg * LPIX + h * HWDIM + w] = bits;
    }
  } else {  // ---- zero g_xt pads (2 x 48 KiB)
    const int idx = (bx - 1176) * 256 + tid;   // 0..6143, 16B each
    uint4 z; z.x = z.y = z.z = z.w = 0u;
    if (idx < 3072)
      reinterpret_cast<uint4*>(g_xt)[idx] = z;
    else
      reinterpret_cast<uint4*>(g_xt + XPAD + (size_t)BATCH * LPIX * CINCH)[idx - 3072] = z;
  }
}

// ---------------------------------------------------------------------------
// GEMM (R8 structure + XCD-aware swizzle). Flat grid of 1080; assuming
// round-robin XCD dispatch (XCD = blockIdx % 8), remap so each XCD owns a
// contiguous band of A-slices (otile,bg,ks): its L2 then holds ~1 MB of g_wa
// + 1.77 MB g_xt -> A-loads become L2 hits instead of HBM-latency misses.
// B staged in LDS once per block; single barrier; 30-chunk unrolled loop.
// Block = 2 waves, tile o64 x l128; wave tile o64 x l64 (4x4 16x16x32 MFMA).
__global__ __launch_bounds__(128, 2) void gemm_masked() {
  __shared__ __align__(16) unsigned char sB[ZOFF + 64];

  const int n = blockIdx.x;                  // 0..1079
  const int m = ((n & 7) * 135) + (n >> 3);  // XCD-contiguous work id
  const int ltile = m % 18;                  // l-tile of 128
  const int s  = m / 18;                     // slice 0..59 = (otile,bg,ks)
  const int otile = s % 3;
  const int zz = s / 3;                      // 0..19
  const int bg = zz & 3;
  const int ks = zz >> 2;                    // kernel row 0..4
  const int b  = bg >> 1;
  const int lbase = ltile * 128, obase = otile * 64;
  const int tid = threadIdx.x, lane = tid & 63, wv = tid >> 6;
  const int q = lane >> 4, m16 = lane & 15;

  // ---- stage window rows [wl0, wl0+131] (contiguous in g_xt) into LDS
  const int wl0 = lbase + (ks - 2) * HWDIM - 2;
  const unsigned short* xwin = g_xt + XPAD + (ptrdiff_t)(b * LPIX + wl0) * CINCH;
  #pragma unroll
  for (int it = 0; it < 25; ++it) {          // 132*24 = 3168 granules of 16 B
    const int i = it * 128 + tid;
    if (it < 24 || i < 3168) {
      const int r = i / 24, g = i % 24;      // src is linear: granule i
      *reinterpret_cast<uint4*>(sB + r * LROW + g * 16) =
          *reinterpret_cast<const uint4*>(xwin + i * 8);
    }
  }
  if (tid < 4) {  // zero line
    uint4 z; z.x = z.y = z.z = z.w = 0u;
    *reinterpret_cast<uint4*>(sB + ZOFF + tid * 16) = z;
  }

  // ---- per-fragment masks (pre-shifted by ks*5) and LDS base offsets
  unsigned bls[4], bhs[4], bboff[4];
  #pragma unroll
  for (int j = 0; j < 4; ++j) {
    const int lj = wv * 64 + j * 16 + m16;
    const unsigned long long bits = g_m64[bg * LPIX + lbase + lj];
    bls[j] = ((unsigned)(bits & 0x1ffffffull)) >> (ks * 5);
    bhs[j] = ((unsigned)((bits >> KTAP) & 0x1ffffffull)) >> (ks * 5);
    bboff[j] = lj * LROW + q * 16;
  }
  const unsigned zoff = ZOFF + q * 16;

  // A base: (bg,t) blob + ot*2048 + (m*4+q)*8 ; frag i at +i*512
  const unsigned short* abase =
      g_wa + ((size_t)bg * NCHUNK + ks * 30) * 6144 + otile * 2048 +
      (m16 * 4 + q) * 8;

  float4v acc[4][4];
  #pragma unroll
  for (int i = 0; i < 4; ++i)
    #pragma unroll
    for (int j = 0; j < 4; ++j) acc[i][j] = (float4v)(0.0f);

  __syncthreads();

  #pragma unroll
  for (int tt = 0; tt < 30; ++tt) {
    const int kt = tt / 6, ci = tt % 6;      // compile-time (full unroll)
    short8 Af[4];
    #pragma unroll
    for (int i = 0; i < 4; ++i)
      Af[i] = *reinterpret_cast<const short8*>(abase + (size_t)tt * 6144 + i * 512);
    short8 Bf[4];
    #pragma unroll
    for (int j = 0; j < 4; ++j) {
      const unsigned bit = (((ci >= 3) ? bhs[j] : bls[j]) >> kt) & 1u;
      const unsigned off = bit ? (bboff[j] + kt * LROW + ci * 64) : zoff;
      Bf[j] = *reinterpret_cast<const short8*>(sB + off);
    }
    #pragma unroll
    for (int i = 0; i < 4; ++i)
      #pragma unroll
      for (int j = 0; j < 4; ++j)
        acc[i][j] = __builtin_amdgcn_mfma_f32_16x16x32_bf16(Af[i], Bf[j],
                                                            acc[i][j], 0, 0, 0);
  }

  // Epilogue: bf16 partial stores to g_part[ks][bg][o][l].
  // C/D layout: col = lane&15, row = q*4 + r.
  unsigned short* pb = g_part + (size_t)ks * OUTEL + (size_t)bg * OG * LPIX;
  #pragma unroll
  for (int i = 0; i < 4; ++i) {
    const int og = obase + i * 16 + q * 4;
    #pragma unroll
    for (int j = 0; j < 4; ++j) {
      const int cl = lbase + wv * 64 + j * 16 + m16;
      #pragma unroll
      for (int r = 0; r < 4; ++r)
        pb[(size_t)(og + r) * LPIX + cl] = f2bf(acc[i][j][r]);
    }
  }
}

// ---------------------------------------------------------------------------
// Reduce: out = sum_ks bf16(g_part[ks]) + bias. 8 elements per thread.
__global__ __launch_bounds__(256) void reduce_part(
    const float* __restrict__ dkb, float* __restrict__ out) {
  const int t8 = blockIdx.x * 256 + threadIdx.x;   // 0..221183
  const size_t e0 = (size_t)t8 * 8;
  const int row = (int)(e0 / LPIX);                // bg*192 + o (8 els same row)
  const float bias = dkb[row];
  float s[8];
  #pragma unroll
  for (int k = 0; k < 8; ++k) s[k] = bias;
  #pragma unroll
  for (int ks = 0; ks < KSPLIT; ++ks) {
    const uint4 v = *reinterpret_cast<const uint4*>(
        g_part + (size_t)ks * OUTEL + e0);
    const unsigned u[4] = {v.x, v.y, v.z, v.w};
    #pragma unroll
    for (int p = 0; p < 4; ++p) {
      union { unsigned u; float f; } lo, hi;
      lo.u = u[p] << 16;
      hi.u = u[p] & 0xffff0000u;
      s[2 * p]     += lo.f;
      s[2 * p + 1] += hi.f;
    }
  }
  float4 o0, o1;
  o0.x = s[0]; o0.y = s[1]; o0.z = s[2]; o0.w = s[3];
  o1.x = s[4]; o1.y = s[5]; o1.z = s[6]; o1.w = s[7];
  reinterpret_cast<float4*>(out)[t8 * 2]     = o0;
  reinterpret_cast<float4*>(out)[t8 * 2 + 1] = o1;
}

// ---------------------------------------------------------------------------
extern "C" void kernel_launch(void* const* d_in, const int* in_sizes, int n_in,
                              void* d_out, int out_size, void* d_ws, size_t ws_size,
                              hipStream_t stream) {
  const float* x   = (const float*)d_in[0];
  const int*   tg  = (const int*)d_in[1];
  const float* dkw = (const float*)d_in[2];
  const float* dkb = (const float*)d_in[3];
  float* out = (float*)d_out;

  prep<<<dim3(1200), 256, 0, stream>>>(x, tg, dkw);
  gemm_masked<<<dim3(1080), 128, 0, stream>>>();
  reduce_part<<<dim3(OUTEL / 2048), 256, 0, stream>>>(dkb, out);
}

// Round 10
// 116.800 us; speedup vs baseline: 1.3791x; 1.0040x over previous
//
#include <hip/hip_runtime.h>
#include <hip/hip_bf16.h>

// Problem constants
#define BATCH 2
#define GRP   2
#define NBG   4            // BATCH*GRP
#define CINCH 192          // input channels
#define OG    192          // output channels per group
#define HWDIM 48
#define LPIX  2304         // 48*48
#define KTAP  25           // 5x5
#define IDIM  4800         // CINCH*KTAP
#define NCHUNK 150         // IDIM/32
#define KSPLIT 5           // one kernel row (5 taps) per split
#define XPAD  24576        // 128 l-rows * 192 c of padding each side of g_xt
#define OUTEL (NBG * OG * LPIX)   // 1769472
#define LROW  400          // LDS bytes per staged row (384 data + 16 pad)
#define ZOFF  (132 * LROW) // zero line offset (52800); LDS total 52864 B

typedef __attribute__((ext_vector_type(4))) float  float4v;
typedef __attribute__((ext_vector_type(8))) short  short8;

// Static device scratch
// A, fragment-major: [bg][t][ot(3)][i(4)][m(16)][q(4)][e(8)] bf16
__device__ __align__(16) unsigned short g_wa[(size_t)NBG * NCHUNK * 6144];
__device__ __align__(16) unsigned short g_xt[XPAD + BATCH * LPIX * CINCH + XPAD]; // [b][l][c] bf16, padded
__device__ unsigned long long g_m64[NBG * LPIX];   // 50 mask bits per (bg,l)
__device__ __align__(16) unsigned short g_part[(size_t)KSPLIT * OUTEL];  // bf16 K-split partials

__device__ __forceinline__ unsigned short f2bf(float f) {
  union { float f; unsigned int u; } un; un.f = f;
  unsigned int u = un.u;
  return (unsigned short)((u + 0x7fffu + ((u >> 16) & 1u)) >> 16);  // RNE
}

// ---------------------------------------------------------------------------
// ONE prep dispatch, block ranges:
//  [0,216)      transpose+cvt x -> g_xt
//  [216,984)    reorder dkw -> g_wa (fragment-major, coalesced 64B stores)
//  [984,1176)   mask bits -> g_m64
//  [1176,1200)  zero g_xt pads
__global__ __launch_bounds__(256) void prep(
    const float* __restrict__ x, const int* __restrict__ tg,
    const float* __restrict__ dkw) {
  __shared__ __align__(16) unsigned char smem[19200];
  const int bx = blockIdx.x, tid = threadIdx.x;

  if (bx < 216) {  // ---- transpose: 64c x 64l tiles via LDS (stride 68)
    unsigned short* tile = (unsigned short*)smem;
    const int c0 = (bx % 3) * 64;
    const int l0 = ((bx / 3) % 36) * 64;
    const int b  = bx / 108;
    #pragma unroll
    for (int it = 0; it < 4; ++it) {
      const int idx = it * 256 + tid;
      const int cl = idx >> 4, lq = idx & 15;
      const float4 v = reinterpret_cast<const float4*>(
          x + ((size_t)b * CINCH + c0 + cl) * LPIX + l0)[lq];
      unsigned short* tp = &tile[cl * 68 + lq * 4];
      tp[0] = f2bf(v.x); tp[1] = f2bf(v.y); tp[2] = f2bf(v.z); tp[3] = f2bf(v.w);
    }
    __syncthreads();
    unsigned short* dst = g_xt + XPAD + ((size_t)b * LPIX) * CINCH;
    #pragma unroll
    for (int it = 0; it < 2; ++it) {
      const int idx = it * 256 + tid;
      const int c8 = idx & 7, ll = idx >> 3;
      unsigned short pk[8];
      #pragma unroll
      for (int e = 0; e < 8; ++e) pk[e] = tile[(c8 * 8 + e) * 68 + ll];
      *reinterpret_cast<uint4*>(dst + (size_t)(l0 + ll) * CINCH + c0 + c8 * 8) =
          *reinterpret_cast<const uint4*>(pk);
    }
  } else if (bx < 984) {  // ---- weight reorder, fragment-major
    float* row = (float*)smem;                 // 4800 floats
    const int blk = bx - 216;                  // bg*192 + o
    const int bg = blk / OG, o = blk % OG;
    const float* src = dkw + (size_t)blk * IDIM;
    for (int i = tid; i < IDIM / 4; i += 256)
      reinterpret_cast<float4*>(row)[i] = reinterpret_cast<const float4*>(src)[i];
    __syncthreads();
    const int ot = o >> 6, fi = (o >> 4) & 3, m = o & 15;
    unsigned short* wbase =
        g_wa + (size_t)bg * NCHUNK * 6144 + ot * 2048 + fi * 512 + m * 32;
    for (int t = tid; t < NCHUNK; t += 256) {  // one 64B granule per t
      const int kk = t / 6, c0 = (t % 6) * 32;
      unsigned int pk[16];
      #pragma unroll
      for (int q = 0; q < 4; ++q)
        #pragma unroll
        for (int e = 0; e < 4; ++e) {
          const int c = c0 + q * 8 + e * 2;
          const unsigned lo = f2bf(row[c * KTAP + kk]);
          const unsigned hi = f2bf(row[(c + 1) * KTAP + kk]);
          pk[q * 4 + e] = lo | (hi << 16);
        }
      unsigned short* dst = wbase + (size_t)t * 6144;
      #pragma unroll
      for (int q = 0; q < 4; ++q)
        reinterpret_cast<uint4*>(dst)[q] = *reinterpret_cast<const uint4*>(pk + q * 4);
    }
  } else if (bx < 1176) {  // ---- mask bits
    const int blk = bx - 984;                  // bg*48 + h
    const int bg = blk / HWDIM, h = blk % HWDIM;
    const int b = bg >> 1, g = bg & 1;
    int* tgs = (int*)smem;                     // [2][5][48]
    for (int i = tid; i < 480; i += 256) {
      const int g2 = i / 240, r5 = (i / 48) % 5, w = i % 48;
      const int hh = h + r5 - 2;
      tgs[i] = (hh >= 0 && hh < HWDIM)
                   ? tg[((b * GRP + g2) * HWDIM + hh) * HWDIM + w]
                   : 0x7fffffff;
    }
    __syncthreads();
    if (tid < HWDIM) {
      const int w = tid;
      const int center = tgs[g * 240 + 96 + w];
      unsigned long long bits = 0ull;
      #pragma unroll
      for (int g2 = 0; g2 < GRP; ++g2)
        #pragma unroll
        for (int kk = 0; kk < KTAP; ++kk) {
          const int ww = w + kk % 5 - 2;
          if (ww >= 0 && ww < HWDIM && tgs[g2 * 240 + (kk / 5) * 48 + ww] < center)
            bits |= 1ull << (g2 * KTAP + kk);
        }
      g_m64[bg * LPIX + h * HWDIM + w] = bits;
    }
  } else {  // ---- zero g_xt pads (2 x 48 KiB)
    const int idx = (bx - 1176) * 256 + tid;   // 0..6143, 16B each
    uint4 z; z.x = z.y = z.z = z.w = 0u;
    if (idx < 3072)
      reinterpret_cast<uint4*>(g_xt)[idx] = z;
    else
      reinterpret_cast<uint4*>(g_xt + XPAD + (size_t)BATCH * LPIX * CINCH)[idx - 3072] = z;
  }
}

// ---------------------------------------------------------------------------
// GEMM (R9 + explicit register pipeline). XCD-aware flat grid of 1080.
// B staged in LDS once per block (contiguous 50.7 KB window, rows padded to
// 400 B); A prefetched 2 chunks deep from global (3 rotating slots, first
// two issued BEFORE the barrier); B frags prefetched 1 chunk deep from LDS.
// Block = 2 waves, tile o64 x l128; wave tile o64 x l64 (4x4 16x16x32 MFMA).
// K-split over kernel rows; bf16 partial stores (no atomics).
__global__ __launch_bounds__(128, 2) void gemm_masked() {
  __shared__ __align__(16) unsigned char sB[ZOFF + 64];

  const int n = blockIdx.x;                  // 0..1079
  const int m = ((n & 7) * 135) + (n >> 3);  // XCD-contiguous work id
  const int ltile = m % 18;                  // l-tile of 128
  const int s  = m / 18;                     // slice 0..59 = (otile,bg,ks)
  const int otile = s % 3;
  const int zz = s / 3;                      // 0..19
  const int bg = zz & 3;
  const int ks = zz >> 2;                    // kernel row 0..4
  const int b  = bg >> 1;
  const int lbase = ltile * 128, obase = otile * 64;
  const int tid = threadIdx.x, lane = tid & 63, wv = tid >> 6;
  const int q = lane >> 4, m16 = lane & 15;

  // A base: (bg,t) blob + ot*2048 + (m*4+q)*8 ; frag i at +i*512
  const unsigned short* abase =
      g_wa + ((size_t)bg * NCHUNK + ks * 30) * 6144 + otile * 2048 +
      (m16 * 4 + q) * 8;

  short8 Af[3][4];   // 2-deep A prefetch (3 rotating slots)
  short8 Bf[2][4];   // 1-deep B prefetch (2 slots)

  #define LOADA(tt)                                                         \
    {                                                                       \
      const int _s = (tt) % 3;                                              \
      _Pragma("unroll")                                                     \
      for (int i = 0; i < 4; ++i)                                           \
        Af[_s][i] = *reinterpret_cast<const short8*>(                       \
            abase + (size_t)(tt) * 6144 + i * 512);                         \
    }

  // issue first two A-chunk loads BEFORE staging/barrier (independent of LDS)
  LOADA(0)
  LOADA(1)

  // ---- stage window rows [wl0, wl0+131] (contiguous in g_xt) into LDS
  const int wl0 = lbase + (ks - 2) * HWDIM - 2;
  const unsigned short* xwin = g_xt + XPAD + (ptrdiff_t)(b * LPIX + wl0) * CINCH;
  #pragma unroll
  for (int it = 0; it < 25; ++it) {          // 132*24 = 3168 granules of 16 B
    const int i = it * 128 + tid;
    if (it < 24 || i < 3168) {
      const int r = i / 24, g = i % 24;      // src is linear: granule i
      *reinterpret_cast<uint4*>(sB + r * LROW + g * 16) =
          *reinterpret_cast<const uint4*>(xwin + i * 8);
    }
  }
  if (tid < 4) {  // zero line
    uint4 z; z.x = z.y = z.z = z.w = 0u;
    *reinterpret_cast<uint4*>(sB + ZOFF + tid * 16) = z;
  }

  // ---- per-fragment masks (pre-shifted by ks*5) and LDS base offsets
  unsigned bls[4], bhs[4], bboff[4];
  #pragma unroll
  for (int j = 0; j < 4; ++j) {
    const int lj = wv * 64 + j * 16 + m16;
    const unsigned long long bits = g_m64[bg * LPIX + lbase + lj];
    bls[j] = ((unsigned)(bits & 0x1ffffffull)) >> (ks * 5);
    bhs[j] = ((unsigned)((bits >> KTAP) & 0x1ffffffull)) >> (ks * 5);
    bboff[j] = lj * LROW + q * 16;
  }
  const unsigned zoff = ZOFF + q * 16;

  #define LOADB(tt)                                                         \
    {                                                                       \
      const int _s = (tt) % 2;                                              \
      const int _kt = (tt) / 6, _ci = (tt) % 6;                             \
      _Pragma("unroll")                                                     \
      for (int j = 0; j < 4; ++j) {                                         \
        const unsigned bit = (((_ci >= 3) ? bhs[j] : bls[j]) >> _kt) & 1u;  \
        const unsigned off =                                                \
            bit ? (bboff[j] + _kt * LROW + _ci * 64) : zoff;                \
        Bf[_s][j] = *reinterpret_cast<const short8*>(sB + off);             \
      }                                                                     \
    }

  float4v acc[4][4];
  #pragma unroll
  for (int i = 0; i < 4; ++i)
    #pragma unroll
    for (int j = 0; j < 4; ++j) acc[i][j] = (float4v)(0.0f);

  __syncthreads();

  LOADB(0)
  #pragma unroll
  for (int tt = 0; tt < 30; ++tt) {
    if (tt + 1 < 30) LOADB(tt + 1)
    if (tt + 2 < 30) LOADA(tt + 2)
    const int sa = tt % 3, sb = tt % 2;
    #pragma unroll
    for (int i = 0; i < 4; ++i)
      #pragma unroll
      for (int j = 0; j < 4; ++j)
        acc[i][j] = __builtin_amdgcn_mfma_f32_16x16x32_bf16(Af[sa][i], Bf[sb][j],
                                                            acc[i][j], 0, 0, 0);
  }
  #undef LOADA
  #undef LOADB

  // Epilogue: bf16 partial stores to g_part[ks][bg][o][l].
  // C/D layout: col = lane&15, row = q*4 + r.
  unsigned short* pb = g_part + (size_t)ks * OUTEL + (size_t)bg * OG * LPIX;
  #pragma unroll
  for (int i = 0; i < 4; ++i) {
    const int og = obase + i * 16 + q * 4;
    #pragma unroll
    for (int j = 0; j < 4; ++j) {
      const int cl = lbase + wv * 64 + j * 16 + m16;
      #pragma unroll
      for (int r = 0; r < 4; ++r)
        pb[(size_t)(og + r) * LPIX + cl] = f2bf(acc[i][j][r]);
    }
  }
}

// ---------------------------------------------------------------------------
// Reduce: out = sum_ks bf16(g_part[ks]) + bias. 8 elements per thread.
__global__ __launch_bounds__(256) void reduce_part(
    const float* __restrict__ dkb, float* __restrict__ out) {
  const int t8 = blockIdx.x * 256 + threadIdx.x;   // 0..221183
  const size_t e0 = (size_t)t8 * 8;
  const int row = (int)(e0 / LPIX);                // bg*192 + o (8 els same row)
  const float bias = dkb[row];
  float s[8];
  #pragma unroll
  for (int k = 0; k < 8; ++k) s[k] = bias;
  #pragma unroll
  for (int ks = 0; ks < KSPLIT; ++ks) {
    const uint4 v = *reinterpret_cast<const uint4*>(
        g_part + (size_t)ks * OUTEL + e0);
    const unsigned u[4] = {v.x, v.y, v.z, v.w};
    #pragma unroll
    for (int p = 0; p < 4; ++p) {
      union { unsigned u; float f; } lo, hi;
      lo.u = u[p] << 16;
      hi.u = u[p] & 0xffff0000u;
      s[2 * p]     += lo.f;
      s[2 * p + 1] += hi.f;
    }
  }
  float4 o0, o1;
  o0.x = s[0]; o0.y = s[1]; o0.z = s[2]; o0.w = s[3];
  o1.x = s[4]; o1.y = s[5]; o1.z = s[6]; o1.w = s[7];
  reinterpret_cast<float4*>(out)[t8 * 2]     = o0;
  reinterpret_cast<float4*>(out)[t8 * 2 + 1] = o1;
}

// ---------------------------------------------------------------------------
extern "C" void kernel_launch(void* const* d_in, const int* in_sizes, int n_in,
                              void* d_out, int out_size, void* d_ws, size_t ws_size,
                              hipStream_t stream) {
  const float* x   = (const float*)d_in[0];
  const int*   tg  = (const int*)d_in[1];
  const float* dkw = (const float*)d_in[2];
  const float* dkb = (const float*)d_in[3];
  float* out = (float*)d_out;

  prep<<<dim3(1200), 256, 0, stream>>>(x, tg, dkw);
  gemm_masked<<<dim3(1080), 128, 0, stream>>>();
  reduce_part<<<dim3(OUTEL / 2048), 256, 0, stream>>>(dkb, out);
}

// Round 11
// 112.851 us; speedup vs baseline: 1.4274x; 1.0350x over previous
//
#include <hip/hip_runtime.h>
#include <hip/hip_bf16.h>

// Problem constants
#define BATCH 2
#define GRP   2
#define NBG   4            // BATCH*GRP
#define CINCH 192          // input channels
#define OG    192          // output channels per group
#define HWDIM 48
#define LPIX  2304         // 48*48
#define KTAP  25           // 5x5
#define IDIM  4800         // CINCH*KTAP
#define NCHUNK 150         // IDIM/32
#define KSPLIT 5           // one kernel row (5 taps) per split
#define XPAD  24576        // 128 l-rows * 192 c of padding each side of g_xt
#define OUTEL (NBG * OG * LPIX)   // 1769472
#define LROW  400          // LDS bytes per staged row (384 data + 16 pad)
#define ZOFF  (132 * LROW) // zero line offset (52800)
#define AOFF  (ZOFF + 64)  // A double-buffer offset; LDS total = AOFF + 16384

typedef __attribute__((ext_vector_type(4))) float  float4v;
typedef __attribute__((ext_vector_type(8))) short  short8;

// Static device scratch
// A, fragment-major: [bg][t][ot(3)][i(4)][m(16)][q(4)][e(8)] bf16
__device__ __align__(16) unsigned short g_wa[(size_t)NBG * NCHUNK * 6144];
__device__ __align__(16) unsigned short g_xt[XPAD + BATCH * LPIX * CINCH + XPAD]; // [b][l][c] bf16, padded
__device__ unsigned long long g_m64[NBG * LPIX];   // 50 mask bits per (bg,l)
__device__ __align__(16) unsigned short g_part[(size_t)KSPLIT * OUTEL];  // bf16 K-split partials

__device__ __forceinline__ unsigned short f2bf(float f) {
  union { float f; unsigned int u; } un; un.f = f;
  unsigned int u = un.u;
  return (unsigned short)((u + 0x7fffu + ((u >> 16) & 1u)) >> 16);  // RNE
}

// ---------------------------------------------------------------------------
// ONE prep dispatch, block ranges:
//  [0,216)      transpose+cvt x -> g_xt
//  [216,984)    reorder dkw -> g_wa (fragment-major, coalesced 64B stores)
//  [984,1176)   mask bits -> g_m64
//  [1176,1200)  zero g_xt pads
__global__ __launch_bounds__(256) void prep(
    const float* __restrict__ x, const int* __restrict__ tg,
    const float* __restrict__ dkw) {
  __shared__ __align__(16) unsigned char smem[19200];
  const int bx = blockIdx.x, tid = threadIdx.x;

  if (bx < 216) {  // ---- transpose: 64c x 64l tiles via LDS (stride 68)
    unsigned short* tile = (unsigned short*)smem;
    const int c0 = (bx % 3) * 64;
    const int l0 = ((bx / 3) % 36) * 64;
    const int b  = bx / 108;
    #pragma unroll
    for (int it = 0; it < 4; ++it) {
      const int idx = it * 256 + tid;
      const int cl = idx >> 4, lq = idx & 15;
      const float4 v = reinterpret_cast<const float4*>(
          x + ((size_t)b * CINCH + c0 + cl) * LPIX + l0)[lq];
      unsigned short* tp = &tile[cl * 68 + lq * 4];
      tp[0] = f2bf(v.x); tp[1] = f2bf(v.y); tp[2] = f2bf(v.z); tp[3] = f2bf(v.w);
    }
    __syncthreads();
    unsigned short* dst = g_xt + XPAD + ((size_t)b * LPIX) * CINCH;
    #pragma unroll
    for (int it = 0; it < 2; ++it) {
      const int idx = it * 256 + tid;
      const int c8 = idx & 7, ll = idx >> 3;
      unsigned short pk[8];
      #pragma unroll
      for (int e = 0; e < 8; ++e) pk[e] = tile[(c8 * 8 + e) * 68 + ll];
      *reinterpret_cast<uint4*>(dst + (size_t)(l0 + ll) * CINCH + c0 + c8 * 8) =
          *reinterpret_cast<const uint4*>(pk);
    }
  } else if (bx < 984) {  // ---- weight reorder, fragment-major
    float* row = (float*)smem;                 // 4800 floats
    const int blk = bx - 216;                  // bg*192 + o
    const int bg = blk / OG, o = blk % OG;
    const float* src = dkw + (size_t)blk * IDIM;
    for (int i = tid; i < IDIM / 4; i += 256)
      reinterpret_cast<float4*>(row)[i] = reinterpret_cast<const float4*>(src)[i];
    __syncthreads();
    const int ot = o >> 6, fi = (o >> 4) & 3, m = o & 15;
    unsigned short* wbase =
        g_wa + (size_t)bg * NCHUNK * 6144 + ot * 2048 + fi * 512 + m * 32;
    for (int t = tid; t < NCHUNK; t += 256) {  // one 64B granule per t
      const int kk = t / 6, c0 = (t % 6) * 32;
      unsigned int pk[16];
      #pragma unroll
      for (int q = 0; q < 4; ++q)
        #pragma unroll
        for (int e = 0; e < 4; ++e) {
          const int c = c0 + q * 8 + e * 2;
          const unsigned lo = f2bf(row[c * KTAP + kk]);
          const unsigned hi = f2bf(row[(c + 1) * KTAP + kk]);
          pk[q * 4 + e] = lo | (hi << 16);
        }
      unsigned short* dst = wbase + (size_t)t * 6144;
      #pragma unroll
      for (int q = 0; q < 4; ++q)
        reinterpret_cast<uint4*>(dst)[q] = *reinterpret_cast<const uint4*>(pk + q * 4);
    }
  } else if (bx < 1176) {  // ---- mask bits
    const int blk = bx - 984;                  // bg*48 + h
    const int bg = blk / HWDIM, h = blk % HWDIM;
    const int b = bg >> 1, g = bg & 1;
    int* tgs = (int*)smem;                     // [2][5][48]
    for (int i = tid; i < 480; i += 256) {
      const int g2 = i / 240, r5 = (i / 48) % 5, w = i % 48;
      const int hh = h + r5 - 2;
      tgs[i] = (hh >= 0 && hh < HWDIM)
                   ? tg[((b * GRP + g2) * HWDIM + hh) * HWDIM + w]
                   : 0x7fffffff;
    }
    __syncthreads();
    if (tid < HWDIM) {
      const int w = tid;
      const int center = tgs[g * 240 + 96 + w];
      unsigned long long bits = 0ull;
      #pragma unroll
      for (int g2 = 0; g2 < GRP; ++g2)
        #pragma unroll
        for (int kk = 0; kk < KTAP; ++kk) {
          const int ww = w + kk % 5 - 2;
          if (ww >= 0 && ww < HWDIM && tgs[g2 * 240 + (kk / 5) * 48 + ww] < center)
            bits |= 1ull << (g2 * KTAP + kk);
        }
      g_m64[bg * LPIX + h * HWDIM + w] = bits;
    }
  } else {  // ---- zero g_xt pads (2 x 48 KiB)
    const int idx = (bx - 1176) * 256 + tid;   // 0..6143, 16B each
    uint4 z; z.x = z.y = z.z = z.w = 0u;
    if (idx < 3072)
      reinterpret_cast<uint4*>(g_xt)[idx] = z;
    else
      reinterpret_cast<uint4*>(g_xt + XPAD + (size_t)BATCH * LPIX * CINCH)[idx - 3072] = z;
  }
}

// ---------------------------------------------------------------------------
// GEMM (R11): A now flows through an LDS double-buffer, staged cooperatively
// per block in 8 KB pairs (2 chunks) with a register round-trip; the vmcnt
// wait on the pair-(pt+1) loads is covered by pair-pt's 32 MFMAs; ONE
// barrier per pair (15 total). B window staged once (52.8 KB, rows padded
// to 400 B); masked B frags redirect to a zeroed LDS line. XCD-aware flat
// grid of 1080. Block = 2 waves, tile o64 x l128; wave tile o64 x l64
// (4x4 16x16x32 MFMA). K-split over kernel rows; bf16 partial stores.
__global__ __launch_bounds__(128, 2) void gemm_masked() {
  __shared__ __align__(16) unsigned char sB[AOFF + 16384];

  const int n = blockIdx.x;                  // 0..1079
  const int m = ((n & 7) * 135) + (n >> 3);  // XCD-contiguous work id
  const int ltile = m % 18;                  // l-tile of 128
  const int s  = m / 18;                     // slice 0..59 = (otile,bg,ks)
  const int otile = s % 3;
  const int zz = s / 3;                      // 0..19
  const int bg = zz & 3;
  const int ks = zz >> 2;                    // kernel row 0..4
  const int b  = bg >> 1;
  const int lbase = ltile * 128, obase = otile * 64;
  const int tid = threadIdx.x, lane = tid & 63, wv = tid >> 6;
  const int q = lane >> 4, m16 = lane & 15;

  // per-thread A staging source: granule tid of this block's chunk slice
  const unsigned short* aslab =
      g_wa + ((size_t)bg * NCHUNK + ks * 30) * 6144 + otile * 2048 + tid * 8;

  uint4 ga[4];   // staged A pair: [cc(2)][p(2)]
  // ---- prologue: issue pair-0 A loads first (independent of LDS)
  #pragma unroll
  for (int cc = 0; cc < 2; ++cc)
    #pragma unroll
    for (int p = 0; p < 2; ++p)
      ga[cc * 2 + p] =
          *reinterpret_cast<const uint4*>(aslab + cc * 6144 + p * 1024);

  // ---- stage window rows [wl0, wl0+131] (contiguous in g_xt) into LDS
  const int wl0 = lbase + (ks - 2) * HWDIM - 2;
  const unsigned short* xwin = g_xt + XPAD + (ptrdiff_t)(b * LPIX + wl0) * CINCH;
  #pragma unroll
  for (int it = 0; it < 25; ++it) {          // 132*24 = 3168 granules of 16 B
    const int i = it * 128 + tid;
    if (it < 24 || i < 3168) {
      const int r = i / 24, g = i % 24;      // src is linear: granule i
      *reinterpret_cast<uint4*>(sB + r * LROW + g * 16) =
          *reinterpret_cast<const uint4*>(xwin + i * 8);
    }
  }
  if (tid < 4) {  // zero line
    uint4 z; z.x = z.y = z.z = z.w = 0u;
    *reinterpret_cast<uint4*>(sB + ZOFF + tid * 16) = z;
  }
  // write A pair 0 into buffer 0
  #pragma unroll
  for (int cc = 0; cc < 2; ++cc)
    #pragma unroll
    for (int p = 0; p < 2; ++p)
      *reinterpret_cast<uint4*>(sB + AOFF + cc * 4096 + tid * 16 + p * 2048) =
          ga[cc * 2 + p];

  // ---- per-fragment masks (pre-shifted by ks*5) and LDS base offsets
  unsigned bls[4], bhs[4], bboff[4];
  #pragma unroll
  for (int j = 0; j < 4; ++j) {
    const int lj = wv * 64 + j * 16 + m16;
    const unsigned long long bits = g_m64[bg * LPIX + lbase + lj];
    bls[j] = ((unsigned)(bits & 0x1ffffffull)) >> (ks * 5);
    bhs[j] = ((unsigned)((bits >> KTAP) & 0x1ffffffull)) >> (ks * 5);
    bboff[j] = lj * LROW + q * 16;
  }
  const unsigned zoff = ZOFF + q * 16;

  short8 Bf[2][4];   // 1-deep B prefetch (2 slots)
  #define LOADB(tt)                                                         \
    {                                                                       \
      const int _s = (tt) & 1;                                              \
      const int _kt = (tt) / 6, _ci = (tt) % 6;                             \
      _Pragma("unroll")                                                     \
      for (int j = 0; j < 4; ++j) {                                         \
        const unsigned bit = (((_ci >= 3) ? bhs[j] : bls[j]) >> _kt) & 1u;  \
        const unsigned off =                                                \
            bit ? (bboff[j] + _kt * LROW + _ci * 64) : zoff;                \
        Bf[_s][j] = *reinterpret_cast<const short8*>(sB + off);             \
      }                                                                     \
    }

  float4v acc[4][4];
  #pragma unroll
  for (int i = 0; i < 4; ++i)
    #pragma unroll
    for (int j = 0; j < 4; ++j) acc[i][j] = (float4v)(0.0f);

  __syncthreads();   // window + A pair 0 visible

  LOADB(0)
  #pragma unroll
  for (int pt = 0; pt < 15; ++pt) {
    // issue global loads for pair pt+1 (consumed by ds_write after compute)
    if (pt < 14) {
      const unsigned short* src = aslab + (size_t)(2 * pt + 2) * 6144;
      #pragma unroll
      for (int cc = 0; cc < 2; ++cc)
        #pragma unroll
        for (int p = 0; p < 2; ++p)
          ga[cc * 2 + p] =
              *reinterpret_cast<const uint4*>(src + cc * 6144 + p * 1024);
    }
    // compute pair pt from A buffer (pt&1)
    #pragma unroll
    for (int cc = 0; cc < 2; ++cc) {
      const int tt = 2 * pt + cc;
      short8 Afr[4];
      #pragma unroll
      for (int i = 0; i < 4; ++i)
        Afr[i] = *reinterpret_cast<const short8*>(
            sB + AOFF + (pt & 1) * 8192 + cc * 4096 + i * 1024 + m16 * 64 + q * 16);
      if (tt + 1 < 30) LOADB(tt + 1)
      const int sb = tt & 1;
      #pragma unroll
      for (int i = 0; i < 4; ++i)
        #pragma unroll
        for (int j = 0; j < 4; ++j)
          acc[i][j] = __builtin_amdgcn_mfma_f32_16x16x32_bf16(Afr[i], Bf[sb][j],
                                                              acc[i][j], 0, 0, 0);
    }
    // write pair pt+1 into the other buffer (safe: last read pair pt-1,
    // separated by the previous barrier), then ONE barrier
    if (pt < 14) {
      unsigned char* dst = sB + AOFF + ((pt + 1) & 1) * 8192;
      #pragma unroll
      for (int cc = 0; cc < 2; ++cc)
        #pragma unroll
        for (int p = 0; p < 2; ++p)
          *reinterpret_cast<uint4*>(dst + cc * 4096 + tid * 16 + p * 2048) =
              ga[cc * 2 + p];
      __syncthreads();
    }
  }
  #undef LOADB

  // Epilogue: bf16 partial stores to g_part[ks][bg][o][l].
  // C/D layout: col = lane&15, row = q*4 + r.
  unsigned short* pb = g_part + (size_t)ks * OUTEL + (size_t)bg * OG * LPIX;
  #pragma unroll
  for (int i = 0; i < 4; ++i) {
    const int og = obase + i * 16 + q * 4;
    #pragma unroll
    for (int j = 0; j < 4; ++j) {
      const int cl = lbase + wv * 64 + j * 16 + m16;
      #pragma unroll
      for (int r = 0; r < 4; ++r)
        pb[(size_t)(og + r) * LPIX + cl] = f2bf(acc[i][j][r]);
    }
  }
}

// ---------------------------------------------------------------------------
// Reduce: out = sum_ks bf16(g_part[ks]) + bias. 8 elements per thread.
__global__ __launch_bounds__(256) void reduce_part(
    const float* __restrict__ dkb, float* __restrict__ out) {
  const int t8 = blockIdx.x * 256 + threadIdx.x;   // 0..221183
  const size_t e0 = (size_t)t8 * 8;
  const int row = (int)(e0 / LPIX);                // bg*192 + o (8 els same row)
  const float bias = dkb[row];
  float s[8];
  #pragma unroll
  for (int k = 0; k < 8; ++k) s[k] = bias;
  #pragma unroll
  for (int ks = 0; ks < KSPLIT; ++ks) {
    const uint4 v = *reinterpret_cast<const uint4*>(
        g_part + (size_t)ks * OUTEL + e0);
    const unsigned u[4] = {v.x, v.y, v.z, v.w};
    #pragma unroll
    for (int p = 0; p < 4; ++p) {
      union { unsigned u; float f; } lo, hi;
      lo.u = u[p] << 16;
      hi.u = u[p] & 0xffff0000u;
      s[2 * p]     += lo.f;
      s[2 * p + 1] += hi.f;
    }
  }
  float4 o0, o1;
  o0.x = s[0]; o0.y = s[1]; o0.z = s[2]; o0.w = s[3];
  o1.x = s[4]; o1.y = s[5]; o1.z = s[6]; o1.w = s[7];
  reinterpret_cast<float4*>(out)[t8 * 2]     = o0;
  reinterpret_cast<float4*>(out)[t8 * 2 + 1] = o1;
}

// ---------------------------------------------------------------------------
extern "C" void kernel_launch(void* const* d_in, const int* in_sizes, int n_in,
                              void* d_out, int out_size, void* d_ws, size_t ws_size,
                              hipStream_t stream) {
  const float* x   = (const float*)d_in[0];
  const int*   tg  = (const int*)d_in[1];
  const float* dkw = (const float*)d_in[2];
  const float* dkb = (const float*)d_in[3];
  float* out = (float*)d_out;

  prep<<<dim3(1200), 256, 0, stream>>>(x, tg, dkw);
  gemm_masked<<<dim3(1080), 128, 0, stream>>>();
  reduce_part<<<dim3(OUTEL / 2048), 256, 0, stream>>>(dkb, out);
}